// Round 13
// baseline (325.770 us; speedup 1.0000x reference)
//
#include <hip/hip_runtime.h>
#include <hip/hip_bf16.h>
#include <math.h>

#define BSZ 2048
#define NNEWS 50000
#define U_NB 30
#define N_NB 30
#define TITLE_LEN 10
#define W_EMB 50
#define DIM 128
#define ROUTIT 4
#define FLAT2 1024        // permuted, zero-padded K

#define CONV_BLOCKS (NNEWS / 8)                       // 6250
#define PREP_ELEMS (DIM * FLAT2 + 2 * DIM * DIM)      // 163,840
#define PREP_BLOCKS (PREP_ELEMS / 256)                // 640
#define DENSE_BLOCKS ((NNEWS + 63) / 64)              // 782

typedef __attribute__((ext_vector_type(8))) short bf16x8;
typedef __attribute__((ext_vector_type(4))) float f32x4;

__device__ __forceinline__ ushort bfbits(float v) {
  __hip_bfloat16 h = __float2bfloat16(v);
  ushort u;
  __builtin_memcpy(&u, &h, 2);
  return u;
}

// Build a bf16x8 A-frag = x[s..s+8) from a 16B-aligned 64-elem bf16 row.
__device__ __forceinline__ bf16x8 bfrag(const ushort* row, int s) {
  const char* p = reinterpret_cast<const char*>(row) + ((s * 2) & ~15);
  const uint4 lo = *reinterpret_cast<const uint4*>(p);
  const uint4 hi = *reinterpret_cast<const uint4*>(p + 16);
  const uint d0 = lo.x, d1 = lo.y, d2 = lo.z, d3 = lo.w;
  const uint d4 = hi.x, d5 = hi.y, d6 = hi.z, d7 = hi.w;
  const bool q2 = (s & 4) != 0;
  const uint e0 = q2 ? d2 : d0, e1 = q2 ? d3 : d1, e2 = q2 ? d4 : d2;
  const uint e3 = q2 ? d5 : d3, e4 = q2 ? d6 : d4, e5 = q2 ? d7 : d5;
  const bool q1 = (s & 2) != 0;
  const uint f0 = q1 ? e1 : e0, f1 = q1 ? e2 : e1, f2 = q1 ? e3 : e2;
  const uint f3 = q1 ? e4 : e3, f4 = q1 ? e5 : e4;
  const bool r1 = (s & 1) != 0;
  uint g[4];
  g[0] = r1 ? ((f0 >> 16) | (f1 << 16)) : f0;
  g[1] = r1 ? ((f1 >> 16) | (f2 << 16)) : f1;
  g[2] = r1 ? ((f2 >> 16) | (f3 << 16)) : f2;
  g[3] = r1 ? ((f3 >> 16) | (f4 << 16)) : f3;
  bf16x8 r;
  __builtin_memcpy(&r, g, 16);
  return r;
}

// ---------------------------------------------------------------------------
// k_front: blocks [0, CONV_BLOCKS) = MFMA Toeplitz conv; blocks
// [CONV_BLOCKS, +PREP_BLOCKS) = weight prep (dwt'/iwt/uwt).
// ---------------------------------------------------------------------------
__global__ __launch_bounds__(256, 4) void k_front(
    const int* __restrict__ title, const float* __restrict__ word_emb,
    const float* __restrict__ conv_w, const float* __restrict__ conv_b,
    const float* __restrict__ dw, const float* __restrict__ iw,
    const float* __restrict__ uw, __hip_bfloat16* __restrict__ flat,
    __hip_bfloat16* __restrict__ dwt, __hip_bfloat16* __restrict__ iwt,
    __hip_bfloat16* __restrict__ uwt) {
  const int tid = threadIdx.x;

  if (blockIdx.x >= CONV_BLOCKS) {  // ---- prep part ----
    const int idx = ((int)blockIdx.x - CONV_BLOCKS) * 256 + tid;
    if (idx < DIM * FLAT2) {
      const int col = idx & 127, k2 = idx >> 7;
      const int i = k2 & 3, X = k2 >> 2;
      const int c = X & 7, gkq = (X >> 3) & 3, jhq = (X >> 5) & 1, h = X >> 6;
      const int j = jhq * 16 + gkq * 4 + i;
      const float v = (j < 31) ? dw[(c * 124 + h * 31 + j) * 128 + col] : 0.f;
      dwt[col * FLAT2 + k2] = __float2bfloat16(v);
    } else if (idx < DIM * FLAT2 + DIM * DIM) {
      const int j = idx - DIM * FLAT2;
      const int o = j & 127, k = j >> 7;
      iwt[o * DIM + k] = __float2bfloat16(iw[j]);
    } else if (idx < PREP_ELEMS) {
      const int j = idx - DIM * FLAT2 - DIM * DIM;
      const int o = j & 127, k = j >> 7;
      uwt[o * DIM + k] = __float2bfloat16(uw[j]);
    }
    return;
  }

  // ---- conv part ----
  __shared__ int s_words[80];
  __shared__ __align__(16) ushort s_x[80 * 64];

  const int wv = tid >> 6, lane = tid & 63;
  const int base = blockIdx.x * 8;
  const int c = lane & 15, gk = lane >> 4;

  bf16x8 b0, b1;
#pragma unroll
  for (int i = 0; i < 8; ++i) {
    const int k = gk * 8 + i;
    float v0 = 0.f, v1 = 0.f;
    if (c < 8 && k < 20) {
      v0 = conv_w[c * 40 + k];
      v1 = conv_w[c * 40 + 20 + k];
    }
    b0[i] = (short)bfbits(v0);
    b1[i] = (short)bfbits(v1);
  }
  const float cbias = (c < 8) ? conv_b[c] : 0.f;

  if (tid < 80) s_words[tid] = title[base * TITLE_LEN + tid];
  __syncthreads();

  {
    const float2* we2 = reinterpret_cast<const float2*>(word_emb);
#pragma unroll
    for (int i = 0; i < 3; ++i) {
      const int u = tid + i * 256;
      if (u < 640) {
        const int row = u >> 3, slot = u & 7;
        ushort o[8];
#pragma unroll
        for (int p = 0; p < 4; ++p) {
          const int c2 = slot * 4 + p;
          float2 v = make_float2(0.f, 0.f);
          if (c2 < 25) v = we2[(long long)s_words[row] * 25 + c2];
          o[2 * p] = bfbits(v.x);
          o[2 * p + 1] = bfbits(v.y);
        }
        *reinterpret_cast<uint4*>(&s_x[row * 64 + slot * 8]) =
            *reinterpret_cast<const uint4*>(o);
      }
    }
  }
  __syncthreads();

  ushort* fl = reinterpret_cast<ushort*>(flat);
#pragma unroll 1
  for (int tt = 0; tt < 2; ++tt) {
    const int t = wv * 2 + tt;
    const ushort* xb = &s_x[t * 640];
    ushort* gout = &fl[(size_t)(base + t) * FLAT2];
#pragma unroll
    for (int jh = 0; jh < 2; ++jh) {
      const int s = jh * 16 + (lane & 15) + gk * 8;
      bf16x8 fprev = bfrag(xb, s);
#pragma unroll
      for (int h = 0; h < 4; ++h) {
        const bf16x8 fmid = bfrag(xb + (2 * h + 1) * 64, s);
        const bf16x8 fnext = bfrag(xb + (2 * h + 2) * 64, s);
        f32x4 d0 = (f32x4){0.f, 0.f, 0.f, 0.f};
        f32x4 d1 = (f32x4){0.f, 0.f, 0.f, 0.f};
        d0 = __builtin_amdgcn_mfma_f32_16x16x32_bf16(fprev, b0, d0, 0, 0, 0);
        d0 = __builtin_amdgcn_mfma_f32_16x16x32_bf16(fmid, b1, d0, 0, 0, 0);
        d1 = __builtin_amdgcn_mfma_f32_16x16x32_bf16(fmid, b0, d1, 0, 0, 0);
        d1 = __builtin_amdgcn_mfma_f32_16x16x32_bf16(fnext, b1, d1, 0, 0, 0);
        if (c < 8) {
          ushort w[4];
#pragma unroll
          for (int i2 = 0; i2 < 4; ++i2)
            w[i2] = bfbits(fmaxf(fmaxf(d0[i2], d1[i2]) + cbias, 0.f));
          *reinterpret_cast<uint2*>(&gout[(h * 64 + jh * 32 + gk * 8 + c) * 4]) =
              *reinterpret_cast<const uint2*>(w);
        }
        fprev = fnext;
      }
    }
  }
}

// ---------------------------------------------------------------------------
// k_dense: [64 x 1024]@[1024 x 128] (+b, relu) then @[128 x 128] (+b, relu).
// ---------------------------------------------------------------------------
__global__ __launch_bounds__(256, 2) void k_dense(
    const __hip_bfloat16* __restrict__ flat,
    const __hip_bfloat16* __restrict__ dwt, const float* __restrict__ dense_b,
    const __hip_bfloat16* __restrict__ iwt, const float* __restrict__ item_b,
    __hip_bfloat16* __restrict__ news_cnn) {
  __shared__ __align__(16) char lds[18432];
  ushort* A0 = (ushort*)lds;
  ushort* A1 = (ushort*)(lds + 9216);
  ushort* c1 = (ushort*)lds;

  const int tid = threadIdx.x;
  const int wv = tid >> 6, lane = tid & 63;
  const int fr = lane & 15, gk = lane >> 4;
  const int lrow0 = min((int)blockIdx.x * 64, NNEWS - 64);
  const ushort* fl = (const ushort*)flat;
  const ushort* dwp = (const ushort*)dwt;

  uint4 pA[2];
#define LD_A(KS)                                                              \
  {                                                                           \
    _Pragma("unroll") for (int q = 0; q < 2; ++q) {                           \
      const int uu = tid + q * 256;                                           \
      pA[q] = *reinterpret_cast<const uint4*>(                                \
          &fl[(size_t)(lrow0 + (uu >> 3)) * FLAT2 + (KS) * 64 + (uu & 7) * 8]); \
    }                                                                         \
  }
#define ST_A(BUF)                                                             \
  {                                                                           \
    _Pragma("unroll") for (int q = 0; q < 2; ++q) {                           \
      const int uu = tid + q * 256;                                           \
      *reinterpret_cast<uint4*>(&(BUF)[(uu >> 3) * 72 + (uu & 7) * 8]) = pA[q]; \
    }                                                                         \
  }
#define LD_B(DST, KS)                                                         \
  {                                                                           \
    _Pragma("unroll") for (int nn = 0; nn < 2; ++nn)                          \
        _Pragma("unroll") for (int qq = 0; qq < 2; ++qq) {                    \
      (DST)[nn * 2 + qq] = *reinterpret_cast<const bf16x8*>(                  \
          &dwp[(wv * 32 + nn * 16 + fr) * FLAT2 + (KS) * 64 + qq * 32 +       \
               gk * 8]);                                                      \
    }                                                                         \
  }

  LD_A(0);
  ST_A(A0);
  LD_A(1);
  bf16x8 bA[4];
  LD_B(bA, 0);
  __syncthreads();

  f32x4 acc[4][2];
#pragma unroll
  for (int m = 0; m < 4; ++m)
#pragma unroll
    for (int n2 = 0; n2 < 2; ++n2) acc[m][n2] = (f32x4){0.f, 0.f, 0.f, 0.f};

  for (int ks = 0; ks < 16; ++ks) {
    const ushort* cA = (ks & 1) ? A1 : A0;
    bf16x8 bN[4];
    if (ks < 15) {
      LD_B(bN, ks + 1);
    } else {
#pragma unroll
      for (int z = 0; z < 4; ++z) bN[z] = bA[z];
    }
    bf16x8 af[2][4];
#pragma unroll
    for (int kk = 0; kk < 2; ++kk)
#pragma unroll
      for (int m = 0; m < 4; ++m)
        af[kk][m] = *reinterpret_cast<const bf16x8*>(
            &cA[(m * 16 + fr) * 72 + kk * 32 + gk * 8]);
#pragma unroll
    for (int kk = 0; kk < 2; ++kk)
#pragma unroll
      for (int m = 0; m < 4; ++m)
#pragma unroll
        for (int n2 = 0; n2 < 2; ++n2)
          acc[m][n2] = __builtin_amdgcn_mfma_f32_16x16x32_bf16(
              af[kk][m], bA[n2 * 2 + kk], acc[m][n2], 0, 0, 0);
    if (ks < 15) {
      if (ks & 1) {
        ST_A(A0);
      } else {
        ST_A(A1);
      }
    }
    if (ks < 14) LD_A(ks + 2);
    __syncthreads();
#pragma unroll
    for (int z = 0; z < 4; ++z) bA[z] = bN[z];
  }
#undef LD_A
#undef ST_A
#undef LD_B

#pragma unroll
  for (int n2 = 0; n2 < 2; ++n2) {
    const int col = wv * 32 + n2 * 16 + fr;
    const float bb = dense_b[col];
#pragma unroll
    for (int m = 0; m < 4; ++m)
#pragma unroll
      for (int r = 0; r < 4; ++r)
        c1[(m * 16 + gk * 4 + r) * 136 + col] =
            bfbits(fmaxf(acc[m][n2][r] + bb, 0.f));
  }
  __syncthreads();

  const ushort* iwp = (const ushort*)iwt;
  f32x4 a2[4][2];
#pragma unroll
  for (int m = 0; m < 4; ++m)
#pragma unroll
    for (int n2 = 0; n2 < 2; ++n2) a2[m][n2] = (f32x4){0.f, 0.f, 0.f, 0.f};
#pragma unroll
  for (int kk = 0; kk < 4; ++kk) {
    bf16x8 af[4], bfr[2];
#pragma unroll
    for (int m = 0; m < 4; ++m)
      af[m] = *reinterpret_cast<const bf16x8*>(
          &c1[(m * 16 + fr) * 136 + kk * 32 + gk * 8]);
#pragma unroll
    for (int n2 = 0; n2 < 2; ++n2)
      bfr[n2] = *reinterpret_cast<const bf16x8*>(
          &iwp[(wv * 32 + n2 * 16 + fr) * DIM + kk * 32 + gk * 8]);
#pragma unroll
    for (int m = 0; m < 4; ++m)
#pragma unroll
      for (int n2 = 0; n2 < 2; ++n2)
        a2[m][n2] = __builtin_amdgcn_mfma_f32_16x16x32_bf16(
            af[m], bfr[n2], a2[m][n2], 0, 0, 0);
  }

#pragma unroll
  for (int n2 = 0; n2 < 2; ++n2) {
    const int col = wv * 32 + n2 * 16 + fr;
    const float bb = item_b[col];
#pragma unroll
    for (int m = 0; m < 4; ++m)
#pragma unroll
      for (int r = 0; r < 4; ++r) {
        const int row = m * 16 + gk * 4 + r;
        news_cnn[(size_t)(lrow0 + row) * DIM + col] =
            __float2bfloat16(fmaxf(a2[m][n2][r] + bb, 0.f));
      }
  }
}

// ---------------------------------------------------------------------------
// k_back: 512 thr/block, block b (unchanged from R12).
// ---------------------------------------------------------------------------
__device__ __forceinline__ float gsum16(float v) {
  v += __shfl_xor(v, 1, 16);
  v += __shfl_xor(v, 2, 16);
  v += __shfl_xor(v, 4, 16);
  v += __shfl_xor(v, 8, 16);
  return v;
}

__global__ __launch_bounds__(512) void k_back(
    const __hip_bfloat16* __restrict__ news_cnn,
    const float* __restrict__ user_emb, const __hip_bfloat16* __restrict__ uwt,
    const float* __restrict__ user_b, const int* __restrict__ user_indices,
    const int* __restrict__ news_indices, const int* __restrict__ news_user,
    const int* __restrict__ user_news, const float* __restrict__ last_w,
    const float* __restrict__ last_b, float* __restrict__ out) {
  __shared__ int s_uid[32];
  __shared__ int s_nid[32];
  __shared__ __align__(16) __hip_bfloat16 s_e[32][136];
  __shared__ __align__(16) float zf2[2][30][132];
  __shared__ __align__(16) float xn2[2][128];
  __shared__ __align__(16) float uu2[2][128];
  __shared__ __align__(16) float pp2[2][30][8];
  __shared__ float s_r[2];

  const int b = blockIdx.x, tid = threadIdx.x;

  if (tid < 32) {
    int uid;
    if (tid == 0 || tid == 31)
      uid = user_indices[b];
    else
      uid = news_user[(long long)news_indices[b] * U_NB + (tid - 1)];
    s_uid[tid] = uid;
  }
  if (tid >= 64 && tid < 94)
    s_nid[tid - 64] = user_news[(long long)user_indices[b] * N_NB + (tid - 64)];
  __syncthreads();

  const int hs = tid >> 8;
  const int t = tid & 255;
  float(*zf)[132] = zf2[hs];
  float* xn = xn2[hs];
  float* uu = uu2[hs];
  float(*pp)[8] = pp2[hs];

  if (tid < 256) {
#pragma unroll
    for (int i = 0; i < 4; ++i) {
      const int u = tid + i * 256;
      const int row = u >> 5, d4 = u & 31;
      const float4 v = *reinterpret_cast<const float4*>(
          &user_emb[(long long)s_uid[row] * DIM + d4 * 4]);
      __hip_bfloat16* p = &s_e[row][d4 * 4];
      p[0] = __float2bfloat16(v.x);
      p[1] = __float2bfloat16(v.y);
      p[2] = __float2bfloat16(v.z);
      p[3] = __float2bfloat16(v.w);
    }
  } else {
    if (t < 240) {
      const int k = t >> 3, q = t & 7;
      const ushort* src =
          reinterpret_cast<const ushort*>(news_cnn + (long long)s_nid[k] * DIM);
      ushort h16[16];
      *reinterpret_cast<uint4*>(&h16[0]) =
          *reinterpret_cast<const uint4*>(&src[q * 16]);
      *reinterpret_cast<uint4*>(&h16[8]) =
          *reinterpret_cast<const uint4*>(&src[q * 16 + 8]);
      float f[16];
#pragma unroll
      for (int i = 0; i < 16; ++i) {
        const uint bits = ((uint)h16[i]) << 16;
        __builtin_memcpy(&f[i], &bits, 4);
      }
#pragma unroll
      for (int v4 = 0; v4 < 4; ++v4)
        *reinterpret_cast<f32x4*>(&zf2[1][k][q * 16 + v4 * 4]) =
            *reinterpret_cast<f32x4*>(&f[v4 * 4]);
    } else {
      const int j = t - 240;
      const ushort* src = reinterpret_cast<const ushort*>(
          news_cnn + (long long)news_indices[b] * DIM);
      ushort h8[8];
      *reinterpret_cast<uint4*>(h8) =
          *reinterpret_cast<const uint4*>(&src[j * 8]);
#pragma unroll
      for (int i = 0; i < 8; ++i) {
        const uint bits = ((uint)h8[i]) << 16;
        float fv;
        __builtin_memcpy(&fv, &bits, 4);
        xn2[0][j * 8 + i] = fv;
      }
    }
  }
  __syncthreads();

  float z16[16];
  const int kk = t >> 3, cc = t & 7;
  if (tid < 256) {
    const int wv = tid >> 6, lane = tid & 63;
    const int fr = lane & 15, gk = lane >> 4;
    const ushort* uwp = (const ushort*)uwt;
    f32x4 acc[2][2];
#pragma unroll
    for (int m = 0; m < 2; ++m)
#pragma unroll
      for (int n = 0; n < 2; ++n) acc[m][n] = (f32x4){0.f, 0.f, 0.f, 0.f};
#pragma unroll
    for (int ks = 0; ks < 4; ++ks) {
      bf16x8 af[2], bfr[2];
#pragma unroll
      for (int m = 0; m < 2; ++m)
        af[m] = *reinterpret_cast<const bf16x8*>(
            &s_e[m * 16 + fr][ks * 32 + gk * 8]);
#pragma unroll
      for (int n = 0; n < 2; ++n)
        bfr[n] = *reinterpret_cast<const bf16x8*>(
            &uwp[(wv * 32 + n * 16 + fr) * DIM + ks * 32 + gk * 8]);
#pragma unroll
      for (int m = 0; m < 2; ++m)
#pragma unroll
        for (int n = 0; n < 2; ++n)
          acc[m][n] = __builtin_amdgcn_mfma_f32_16x16x32_bf16(
              af[m], bfr[n], acc[m][n], 0, 0, 0);
    }
#pragma unroll
    for (int n = 0; n < 2; ++n) {
      const int col = wv * 32 + n * 16 + fr;
      const float bb = user_b[col];
#pragma unroll
      for (int m = 0; m < 2; ++m)
#pragma unroll
        for (int r = 0; r < 4; ++r) {
          const int row = m * 16 + gk * 4 + r;
          const float val = fmaxf(acc[m][n][r] + bb, 0.f);
          if (row == 0)
            xn2[1][col] = val;
          else if (row < 31)
            zf2[0][row - 1][col] = val;
        }
    }
  } else if (t < 240) {
    float ss = 0.f;
#pragma unroll
    for (int d = 0; d < 16; ++d) {
      z16[d] = zf2[1][kk][cc * 16 + d];
      ss += z16[d] * z16[d];
    }
    const float inv = 1.f / (sqrtf(ss) + 1e-9f);
#pragma unroll
    for (int d = 0; d < 16; ++d) {
      z16[d] *= inv;
      zf2[1][kk][cc * 16 + d] = z16[d];
    }
  }
  __syncthreads();

  if (hs == 0 && t < 240) {
    float ss = 0.f;
#pragma unroll
    for (int d = 0; d < 16; ++d) {
      z16[d] = zf2[0][kk][cc * 16 + d];
      ss += z16[d] * z16[d];
    }
    const float inv = 1.f / (sqrtf(ss) + 1e-9f);
#pragma unroll
    for (int d = 0; d < 16; ++d) {
      z16[d] *= inv;
      zf2[0][kk][cc * 16 + d] = z16[d];
    }
  }
  if (t < 128) {
    float xv = xn[t];
    xv = xv / (sqrtf(gsum16(xv * xv)) + 1e-9f);
    xn[t] = xv;
    uu[t] = xv;
  }
  __syncthreads();

  for (int it = 0; it < ROUTIT; ++it) {
    if (t < 240) {
      float dot = 0.f;
#pragma unroll
      for (int d = 0; d < 16; ++d) dot += z16[d] * uu[cc * 16 + d];
      float m8 = dot;
      m8 = fmaxf(m8, __shfl_xor(m8, 1, 8));
      m8 = fmaxf(m8, __shfl_xor(m8, 2, 8));
      m8 = fmaxf(m8, __shfl_xor(m8, 4, 8));
      float e = expf(dot - m8);
      float s8 = e;
      s8 += __shfl_xor(s8, 1, 8);
      s8 += __shfl_xor(s8, 2, 8);
      s8 += __shfl_xor(s8, 4, 8);
      pp[kk][cc] = e / s8;
    }
    __syncthreads();
    if (t < 128) {
      const int c2 = t >> 4;
      float agg = xn[t];
#pragma unroll
      for (int k = 0; k < 30; ++k) agg += pp[k][c2] * zf[k][t];
      uu[t] = agg / (sqrtf(gsum16(agg * agg)) + 1e-9f);
    }
    __syncthreads();
  }

  if (tid < 128) {
    float xm = last_b[tid], ym = xm;
    for (int k = 0; k < DIM; k += 4) {
#pragma unroll
      for (int i = 0; i < 4; ++i) {
        const float w = last_w[(k + i) * DIM + tid];
        xm += uu2[1][k + i] * w;
        ym += uu2[0][k + i] * w;
      }
    }
    float prod = xm * ym;
#pragma unroll
    for (int off = 1; off < 64; off <<= 1) prod += __shfl_xor(prod, off, 64);
    if ((tid & 63) == 0) s_r[tid >> 6] = prod;
  }
  __syncthreads();
  if (tid == 0) out[b] = 1.f / (1.f + expf(-(s_r[0] + s_r[1])));
}

// ---------------------------------------------------------------------------
// INSTRUMENTATION ROUND: k_front and k_dense are launched TWICE (idempotent
// pure functions -> identical results). Marginal total time = F + D.
// ---------------------------------------------------------------------------
extern "C" void kernel_launch(void* const* d_in, const int* in_sizes, int n_in,
                              void* d_out, int out_size, void* d_ws,
                              size_t ws_size, hipStream_t stream) {
  (void)in_sizes; (void)n_in; (void)out_size; (void)ws_size;
  const int* user_indices = (const int*)d_in[0];
  const int* news_indices = (const int*)d_in[1];
  const int* news_user = (const int*)d_in[3];
  const int* user_news = (const int*)d_in[4];
  const int* title = (const int*)d_in[5];
  const float* user_emb_matrix = (const float*)d_in[6];
  const float* word_emb_matrix = (const float*)d_in[7];
  const float* conv_w = (const float*)d_in[8];
  const float* conv_b = (const float*)d_in[9];
  const float* dense_w = (const float*)d_in[10];
  const float* dense_b = (const float*)d_in[11];
  const float* user_weights = (const float*)d_in[12];
  const float* user_bias = (const float*)d_in[13];
  const float* item_weights = (const float*)d_in[14];
  const float* item_bias = (const float*)d_in[15];
  const float* last_w = (const float*)d_in[16];
  const float* last_b = (const float*)d_in[17];

  char* ws = (char*)d_ws;
  __hip_bfloat16* flat = (__hip_bfloat16*)ws;            // 102.4 MB
  ws += (size_t)NNEWS * FLAT2 * 2;
  __hip_bfloat16* news_cnn = (__hip_bfloat16*)ws;        // 12.8 MB
  ws += (size_t)NNEWS * DIM * 2;
  __hip_bfloat16* dwt = (__hip_bfloat16*)ws;             // 262,144 B
  ws += (size_t)DIM * FLAT2 * 2;
  __hip_bfloat16* iwt = (__hip_bfloat16*)ws;
  ws += (size_t)DIM * DIM * 2;
  __hip_bfloat16* uwt = (__hip_bfloat16*)ws;
  float* out = (float*)d_out;

  k_front<<<CONV_BLOCKS + PREP_BLOCKS, 256, 0, stream>>>(
      title, word_emb_matrix, conv_w, conv_b, dense_w, item_weights,
      user_weights, flat, dwt, iwt, uwt);
  k_front<<<CONV_BLOCKS + PREP_BLOCKS, 256, 0, stream>>>(
      title, word_emb_matrix, conv_w, conv_b, dense_w, item_weights,
      user_weights, flat, dwt, iwt, uwt);
  k_dense<<<DENSE_BLOCKS, 256, 0, stream>>>(flat, dwt, dense_b, iwt, item_bias,
                                            news_cnn);
  k_dense<<<DENSE_BLOCKS, 256, 0, stream>>>(flat, dwt, dense_b, iwt, item_bias,
                                            news_cnn);
  k_back<<<BSZ, 512, 0, stream>>>(news_cnn, user_emb_matrix, uwt, user_bias,
                                  user_indices, news_indices, news_user,
                                  user_news, last_w, last_b, out);
}

// Round 14
// 245.818 us; speedup vs baseline: 1.3252x; 1.3252x over previous
//
#include <hip/hip_runtime.h>
#include <hip/hip_bf16.h>
#include <math.h>

#define BSZ 2048
#define NNEWS 50000
#define U_NB 30
#define N_NB 30
#define TITLE_LEN 10
#define W_EMB 50
#define DIM 128
#define ROUTIT 4
#define FLAT2 1024        // permuted, zero-padded K
#define TPB 16            // titles per fused block
#define SFLD 1032         // padded s_flat row (ushort) -> 2-way banks

#define PREP_ELEMS (DIM * FLAT2 + 2 * DIM * DIM)      // 163,840
#define NEWS_BLOCKS (NNEWS / TPB)                     // 3125

typedef __attribute__((ext_vector_type(8))) short bf16x8;
typedef __attribute__((ext_vector_type(4))) float f32x4;

__device__ __forceinline__ ushort bfbits(float v) {
  __hip_bfloat16 h = __float2bfloat16(v);
  ushort u;
  __builtin_memcpy(&u, &h, 2);
  return u;
}

// Build a bf16x8 A-frag = x[s..s+8) from a 16B-aligned 64-elem bf16 row.
__device__ __forceinline__ bf16x8 bfrag(const ushort* row, int s) {
  const char* p = reinterpret_cast<const char*>(row) + ((s * 2) & ~15);
  const uint4 lo = *reinterpret_cast<const uint4*>(p);
  const uint4 hi = *reinterpret_cast<const uint4*>(p + 16);
  const uint d0 = lo.x, d1 = lo.y, d2 = lo.z, d3 = lo.w;
  const uint d4 = hi.x, d5 = hi.y, d6 = hi.z, d7 = hi.w;
  const bool q2 = (s & 4) != 0;
  const uint e0 = q2 ? d2 : d0, e1 = q2 ? d3 : d1, e2 = q2 ? d4 : d2;
  const uint e3 = q2 ? d5 : d3, e4 = q2 ? d6 : d4, e5 = q2 ? d7 : d5;
  const bool q1 = (s & 2) != 0;
  const uint f0 = q1 ? e1 : e0, f1 = q1 ? e2 : e1, f2 = q1 ? e3 : e2;
  const uint f3 = q1 ? e4 : e3, f4 = q1 ? e5 : e4;
  const bool r1 = (s & 1) != 0;
  uint g[4];
  g[0] = r1 ? ((f0 >> 16) | (f1 << 16)) : f0;
  g[1] = r1 ? ((f1 >> 16) | (f2 << 16)) : f1;
  g[2] = r1 ? ((f2 >> 16) | (f3 << 16)) : f2;
  g[3] = r1 ? ((f3 >> 16) | (f4 << 16)) : f3;
  bf16x8 r;
  __builtin_memcpy(&r, g, 16);
  return r;
}

// ---------------------------------------------------------------------------
// k_prep: dwt' (permuted zero-padded K=1024) + transposed iwt/uwt.
// ---------------------------------------------------------------------------
__global__ __launch_bounds__(256) void k_prep(
    const float* __restrict__ dw, const float* __restrict__ iw,
    const float* __restrict__ uw, __hip_bfloat16* __restrict__ dwt,
    __hip_bfloat16* __restrict__ iwt, __hip_bfloat16* __restrict__ uwt) {
  const int idx = blockIdx.x * 256 + threadIdx.x;
  if (idx < DIM * FLAT2) {
    const int col = idx & 127, k2 = idx >> 7;
    const int i = k2 & 3, X = k2 >> 2;
    const int c = X & 7, gkq = (X >> 3) & 3, jhq = (X >> 5) & 1, h = X >> 6;
    const int j = jhq * 16 + gkq * 4 + i;
    const float v = (j < 31) ? dw[(c * 124 + h * 31 + j) * 128 + col] : 0.f;
    dwt[col * FLAT2 + k2] = __float2bfloat16(v);
  } else if (idx < DIM * FLAT2 + DIM * DIM) {
    const int j = idx - DIM * FLAT2;
    const int o = j & 127, k = j >> 7;
    iwt[o * DIM + k] = __float2bfloat16(iw[j]);
  } else if (idx < PREP_ELEMS) {
    const int j = idx - DIM * FLAT2 - DIM * DIM;
    const int o = j & 127, k = j >> 7;
    uwt[o * DIM + k] = __float2bfloat16(uw[j]);
  }
}

// ---------------------------------------------------------------------------
// k_news: FUSED conv -> dense -> item for 16 titles/block, 256 thr, 2 blk/CU.
// conv writes s_flat (LDS, padded rows); dense reads A from LDS, B (dwt)
// register-prefetched from L2; item from c1 overlay; out -> news_cnn.
// ---------------------------------------------------------------------------
__global__ __launch_bounds__(256, 2) void k_news(
    const int* __restrict__ title, const float* __restrict__ word_emb,
    const float* __restrict__ conv_w, const float* __restrict__ conv_b,
    const __hip_bfloat16* __restrict__ dwt, const float* __restrict__ dense_b,
    const __hip_bfloat16* __restrict__ iwt, const float* __restrict__ item_b,
    __hip_bfloat16* __restrict__ news_cnn) {
  __shared__ int s_words[TPB * TITLE_LEN];                 // 640 B
  __shared__ __align__(16) ushort s_x[TPB * 640];          // 20,480 B
  __shared__ __align__(16) ushort s_flat[TPB * SFLD];      // 33,024 B
  ushort* c1 = s_x;                                        // [16][136] overlay

  const int tid = threadIdx.x;
  const int wv = tid >> 6, lane = tid & 63;
  const int base = blockIdx.x * TPB;
  const int c = lane & 15, gk = lane >> 4;
  const int fr = lane & 15;

  // conv B-frags (weights); taps >=20 zeroed in B
  bf16x8 b0, b1;
#pragma unroll
  for (int i = 0; i < 8; ++i) {
    const int k = gk * 8 + i;
    float v0 = 0.f, v1 = 0.f;
    if (c < 8 && k < 20) {
      v0 = conv_w[c * 40 + k];
      v1 = conv_w[c * 40 + 20 + k];
    }
    b0[i] = (short)bfbits(v0);
    b1[i] = (short)bfbits(v1);
  }
  const float cbias = (c < 8) ? conv_b[c] : 0.f;

  if (tid < TPB * TITLE_LEN) s_words[tid] = title[base * TITLE_LEN + tid];
  __syncthreads();

  // gather: 160 rows x 64 bf16 (elems 50..63 zero); 1280 uint4 writes
  {
    const float2* we2 = reinterpret_cast<const float2*>(word_emb);
#pragma unroll
    for (int i = 0; i < 5; ++i) {
      const int u = tid + i * 256;  // < 1280 always
      const int row = u >> 3, slot = u & 7;
      ushort o[8];
#pragma unroll
      for (int p = 0; p < 4; ++p) {
        const int c2 = slot * 4 + p;
        float2 v = make_float2(0.f, 0.f);
        if (c2 < 25) v = we2[(long long)s_words[row] * 25 + c2];
        o[2 * p] = bfbits(v.x);
        o[2 * p + 1] = bfbits(v.y);
      }
      *reinterpret_cast<uint4*>(&s_x[row * 64 + slot * 8]) =
          *reinterpret_cast<const uint4*>(o);
    }
  }
  __syncthreads();

  // conv via MFMA: wave wv handles titles {p*8 + wv*2 + tt}
#pragma unroll 1
  for (int p = 0; p < 2; ++p) {
#pragma unroll 1
    for (int tt = 0; tt < 2; ++tt) {
      const int t = p * 8 + wv * 2 + tt;
      const ushort* xb = &s_x[t * 640];
      ushort* fout = &s_flat[t * SFLD];
#pragma unroll
      for (int jh = 0; jh < 2; ++jh) {
        const int s = jh * 16 + fr + gk * 8;
        bf16x8 fprev = bfrag(xb, s);
#pragma unroll
        for (int h = 0; h < 4; ++h) {
          const bf16x8 fmid = bfrag(xb + (2 * h + 1) * 64, s);
          const bf16x8 fnext = bfrag(xb + (2 * h + 2) * 64, s);
          f32x4 d0 = (f32x4){0.f, 0.f, 0.f, 0.f};
          f32x4 d1 = (f32x4){0.f, 0.f, 0.f, 0.f};
          d0 = __builtin_amdgcn_mfma_f32_16x16x32_bf16(fprev, b0, d0, 0, 0, 0);
          d0 = __builtin_amdgcn_mfma_f32_16x16x32_bf16(fmid, b1, d0, 0, 0, 0);
          d1 = __builtin_amdgcn_mfma_f32_16x16x32_bf16(fmid, b0, d1, 0, 0, 0);
          d1 = __builtin_amdgcn_mfma_f32_16x16x32_bf16(fnext, b1, d1, 0, 0, 0);
          if (c < 8) {
            ushort w[4];
#pragma unroll
            for (int i2 = 0; i2 < 4; ++i2)
              w[i2] = bfbits(fmaxf(fmaxf(d0[i2], d1[i2]) + cbias, 0.f));
            *reinterpret_cast<uint2*>(
                &fout[(h * 64 + jh * 32 + gk * 8 + c) * 4]) =
                *reinterpret_cast<const uint2*>(w);
          }
          fprev = fnext;
        }
      }
    }
  }
  __syncthreads();

  // dense GEMM [16 x 1024] @ dwt^T -> c1 (relu,+b).  wave wv: cols 32wv..+32.
  const ushort* dwp = (const ushort*)dwt;
  bf16x8 bA[4], bN[4];
#define LD_B(DST, KS)                                                         \
  {                                                                           \
    _Pragma("unroll") for (int nn = 0; nn < 2; ++nn)                          \
        _Pragma("unroll") for (int qq = 0; qq < 2; ++qq) {                    \
      (DST)[nn * 2 + qq] = *reinterpret_cast<const bf16x8*>(                  \
          &dwp[(wv * 32 + nn * 16 + fr) * FLAT2 + (KS) * 64 + qq * 32 +       \
               gk * 8]);                                                      \
    }                                                                         \
  }
  LD_B(bA, 0);
  f32x4 acc[2];
  acc[0] = (f32x4){0.f, 0.f, 0.f, 0.f};
  acc[1] = (f32x4){0.f, 0.f, 0.f, 0.f};

  for (int ks = 0; ks < 16; ++ks) {
    if (ks < 15) {
      LD_B(bN, ks + 1);
    }
    bf16x8 af[2];
#pragma unroll
    for (int kk = 0; kk < 2; ++kk)
      af[kk] = *reinterpret_cast<const bf16x8*>(
          &s_flat[fr * SFLD + ks * 64 + kk * 32 + gk * 8]);
#pragma unroll
    for (int kk = 0; kk < 2; ++kk)
#pragma unroll
      for (int n = 0; n < 2; ++n)
        acc[n] = __builtin_amdgcn_mfma_f32_16x16x32_bf16(af[kk], bA[n * 2 + kk],
                                                         acc[n], 0, 0, 0);
    if (ks < 15) {
#pragma unroll
      for (int z = 0; z < 4; ++z) bA[z] = bN[z];
    }
  }
#undef LD_B
  __syncthreads();  // all s_flat reads done; c1 (overlay of s_x) write next

  // epilogue -> c1[16][136]
#pragma unroll
  for (int n = 0; n < 2; ++n) {
    const int col = wv * 32 + n * 16 + fr;
    const float bb = dense_b[col];
#pragma unroll
    for (int r = 0; r < 4; ++r)
      c1[(gk * 4 + r) * 136 + col] = bfbits(fmaxf(acc[n][r] + bb, 0.f));
  }
  __syncthreads();

  // item GEMM [16 x 128] @ iwt^T (+b, relu) -> news_cnn
  const ushort* iwp = (const ushort*)iwt;
  f32x4 a2[2];
  a2[0] = (f32x4){0.f, 0.f, 0.f, 0.f};
  a2[1] = (f32x4){0.f, 0.f, 0.f, 0.f};
#pragma unroll
  for (int kk = 0; kk < 4; ++kk) {
    const bf16x8 af = *reinterpret_cast<const bf16x8*>(
        &c1[fr * 136 + kk * 32 + gk * 8]);
#pragma unroll
    for (int n = 0; n < 2; ++n) {
      const bf16x8 bfr = *reinterpret_cast<const bf16x8*>(
          &iwp[(wv * 32 + n * 16 + fr) * DIM + kk * 32 + gk * 8]);
      a2[n] = __builtin_amdgcn_mfma_f32_16x16x32_bf16(af, bfr, a2[n], 0, 0, 0);
    }
  }
#pragma unroll
  for (int n = 0; n < 2; ++n) {
    const int col = wv * 32 + n * 16 + fr;
    const float bb = item_b[col];
#pragma unroll
    for (int r = 0; r < 4; ++r) {
      const int row = gk * 4 + r;
      news_cnn[(size_t)(base + row) * DIM + col] =
          __float2bfloat16(fmaxf(a2[n][r] + bb, 0.f));
    }
  }
}

// ---------------------------------------------------------------------------
// k_back: 512 thr/block, block b (unchanged from R12).
// ---------------------------------------------------------------------------
__device__ __forceinline__ float gsum16(float v) {
  v += __shfl_xor(v, 1, 16);
  v += __shfl_xor(v, 2, 16);
  v += __shfl_xor(v, 4, 16);
  v += __shfl_xor(v, 8, 16);
  return v;
}

__global__ __launch_bounds__(512) void k_back(
    const __hip_bfloat16* __restrict__ news_cnn,
    const float* __restrict__ user_emb, const __hip_bfloat16* __restrict__ uwt,
    const float* __restrict__ user_b, const int* __restrict__ user_indices,
    const int* __restrict__ news_indices, const int* __restrict__ news_user,
    const int* __restrict__ user_news, const float* __restrict__ last_w,
    const float* __restrict__ last_b, float* __restrict__ out) {
  __shared__ int s_uid[32];
  __shared__ int s_nid[32];
  __shared__ __align__(16) __hip_bfloat16 s_e[32][136];
  __shared__ __align__(16) float zf2[2][30][132];
  __shared__ __align__(16) float xn2[2][128];
  __shared__ __align__(16) float uu2[2][128];
  __shared__ __align__(16) float pp2[2][30][8];
  __shared__ float s_r[2];

  const int b = blockIdx.x, tid = threadIdx.x;

  if (tid < 32) {
    int uid;
    if (tid == 0 || tid == 31)
      uid = user_indices[b];
    else
      uid = news_user[(long long)news_indices[b] * U_NB + (tid - 1)];
    s_uid[tid] = uid;
  }
  if (tid >= 64 && tid < 94)
    s_nid[tid - 64] = user_news[(long long)user_indices[b] * N_NB + (tid - 64)];
  __syncthreads();

  const int hs = tid >> 8;
  const int t = tid & 255;
  float(*zf)[132] = zf2[hs];
  float* xn = xn2[hs];
  float* uu = uu2[hs];
  float(*pp)[8] = pp2[hs];

  if (tid < 256) {
#pragma unroll
    for (int i = 0; i < 4; ++i) {
      const int u = tid + i * 256;
      const int row = u >> 5, d4 = u & 31;
      const float4 v = *reinterpret_cast<const float4*>(
          &user_emb[(long long)s_uid[row] * DIM + d4 * 4]);
      __hip_bfloat16* p = &s_e[row][d4 * 4];
      p[0] = __float2bfloat16(v.x);
      p[1] = __float2bfloat16(v.y);
      p[2] = __float2bfloat16(v.z);
      p[3] = __float2bfloat16(v.w);
    }
  } else {
    if (t < 240) {
      const int k = t >> 3, q = t & 7;
      const ushort* src =
          reinterpret_cast<const ushort*>(news_cnn + (long long)s_nid[k] * DIM);
      ushort h16[16];
      *reinterpret_cast<uint4*>(&h16[0]) =
          *reinterpret_cast<const uint4*>(&src[q * 16]);
      *reinterpret_cast<uint4*>(&h16[8]) =
          *reinterpret_cast<const uint4*>(&src[q * 16 + 8]);
      float f[16];
#pragma unroll
      for (int i = 0; i < 16; ++i) {
        const uint bits = ((uint)h16[i]) << 16;
        __builtin_memcpy(&f[i], &bits, 4);
      }
#pragma unroll
      for (int v4 = 0; v4 < 4; ++v4)
        *reinterpret_cast<f32x4*>(&zf2[1][k][q * 16 + v4 * 4]) =
            *reinterpret_cast<f32x4*>(&f[v4 * 4]);
    } else {
      const int j = t - 240;
      const ushort* src = reinterpret_cast<const ushort*>(
          news_cnn + (long long)news_indices[b] * DIM);
      ushort h8[8];
      *reinterpret_cast<uint4*>(h8) =
          *reinterpret_cast<const uint4*>(&src[j * 8]);
#pragma unroll
      for (int i = 0; i < 8; ++i) {
        const uint bits = ((uint)h8[i]) << 16;
        float fv;
        __builtin_memcpy(&fv, &bits, 4);
        xn2[0][j * 8 + i] = fv;
      }
    }
  }
  __syncthreads();

  float z16[16];
  const int kk = t >> 3, cc = t & 7;
  if (tid < 256) {
    const int wv = tid >> 6, lane = tid & 63;
    const int fr = lane & 15, gk = lane >> 4;
    const ushort* uwp = (const ushort*)uwt;
    f32x4 acc[2][2];
#pragma unroll
    for (int m = 0; m < 2; ++m)
#pragma unroll
      for (int n = 0; n < 2; ++n) acc[m][n] = (f32x4){0.f, 0.f, 0.f, 0.f};
#pragma unroll
    for (int ks = 0; ks < 4; ++ks) {
      bf16x8 af[2], bfr[2];
#pragma unroll
      for (int m = 0; m < 2; ++m)
        af[m] = *reinterpret_cast<const bf16x8*>(
            &s_e[m * 16 + fr][ks * 32 + gk * 8]);
#pragma unroll
      for (int n = 0; n < 2; ++n)
        bfr[n] = *reinterpret_cast<const bf16x8*>(
            &uwp[(wv * 32 + n * 16 + fr) * DIM + ks * 32 + gk * 8]);
#pragma unroll
      for (int m = 0; m < 2; ++m)
#pragma unroll
        for (int n = 0; n < 2; ++n)
          acc[m][n] = __builtin_amdgcn_mfma_f32_16x16x32_bf16(
              af[m], bfr[n], acc[m][n], 0, 0, 0);
    }
#pragma unroll
    for (int n = 0; n < 2; ++n) {
      const int col = wv * 32 + n * 16 + fr;
      const float bb = user_b[col];
#pragma unroll
      for (int m = 0; m < 2; ++m)
#pragma unroll
        for (int r = 0; r < 4; ++r) {
          const int row = m * 16 + gk * 4 + r;
          const float val = fmaxf(acc[m][n][r] + bb, 0.f);
          if (row == 0)
            xn2[1][col] = val;
          else if (row < 31)
            zf2[0][row - 1][col] = val;
        }
    }
  } else if (t < 240) {
    float ss = 0.f;
#pragma unroll
    for (int d = 0; d < 16; ++d) {
      z16[d] = zf2[1][kk][cc * 16 + d];
      ss += z16[d] * z16[d];
    }
    const float inv = 1.f / (sqrtf(ss) + 1e-9f);
#pragma unroll
    for (int d = 0; d < 16; ++d) {
      z16[d] *= inv;
      zf2[1][kk][cc * 16 + d] = z16[d];
    }
  }
  __syncthreads();

  if (hs == 0 && t < 240) {
    float ss = 0.f;
#pragma unroll
    for (int d = 0; d < 16; ++d) {
      z16[d] = zf2[0][kk][cc * 16 + d];
      ss += z16[d] * z16[d];
    }
    const float inv = 1.f / (sqrtf(ss) + 1e-9f);
#pragma unroll
    for (int d = 0; d < 16; ++d) {
      z16[d] *= inv;
      zf2[0][kk][cc * 16 + d] = z16[d];
    }
  }
  if (t < 128) {
    float xv = xn[t];
    xv = xv / (sqrtf(gsum16(xv * xv)) + 1e-9f);
    xn[t] = xv;
    uu[t] = xv;
  }
  __syncthreads();

  for (int it = 0; it < ROUTIT; ++it) {
    if (t < 240) {
      float dot = 0.f;
#pragma unroll
      for (int d = 0; d < 16; ++d) dot += z16[d] * uu[cc * 16 + d];
      float m8 = dot;
      m8 = fmaxf(m8, __shfl_xor(m8, 1, 8));
      m8 = fmaxf(m8, __shfl_xor(m8, 2, 8));
      m8 = fmaxf(m8, __shfl_xor(m8, 4, 8));
      float e = expf(dot - m8);
      float s8 = e;
      s8 += __shfl_xor(s8, 1, 8);
      s8 += __shfl_xor(s8, 2, 8);
      s8 += __shfl_xor(s8, 4, 8);
      pp[kk][cc] = e / s8;
    }
    __syncthreads();
    if (t < 128) {
      const int c2 = t >> 4;
      float agg = xn[t];
#pragma unroll
      for (int k = 0; k < 30; ++k) agg += pp[k][c2] * zf[k][t];
      uu[t] = agg / (sqrtf(gsum16(agg * agg)) + 1e-9f);
    }
    __syncthreads();
  }

  if (tid < 128) {
    float xm = last_b[tid], ym = xm;
    for (int k = 0; k < DIM; k += 4) {
#pragma unroll
      for (int i = 0; i < 4; ++i) {
        const float w = last_w[(k + i) * DIM + tid];
        xm += uu2[1][k + i] * w;
        ym += uu2[0][k + i] * w;
      }
    }
    float prod = xm * ym;
#pragma unroll
    for (int off = 1; off < 64; off <<= 1) prod += __shfl_xor(prod, off, 64);
    if ((tid & 63) == 0) s_r[tid >> 6] = prod;
  }
  __syncthreads();
  if (tid == 0) out[b] = 1.f / (1.f + expf(-(s_r[0] + s_r[1])));
}

// ---------------------------------------------------------------------------
extern "C" void kernel_launch(void* const* d_in, const int* in_sizes, int n_in,
                              void* d_out, int out_size, void* d_ws,
                              size_t ws_size, hipStream_t stream) {
  (void)in_sizes; (void)n_in; (void)out_size; (void)ws_size;
  const int* user_indices = (const int*)d_in[0];
  const int* news_indices = (const int*)d_in[1];
  const int* news_user = (const int*)d_in[3];
  const int* user_news = (const int*)d_in[4];
  const int* title = (const int*)d_in[5];
  const float* user_emb_matrix = (const float*)d_in[6];
  const float* word_emb_matrix = (const float*)d_in[7];
  const float* conv_w = (const float*)d_in[8];
  const float* conv_b = (const float*)d_in[9];
  const float* dense_w = (const float*)d_in[10];
  const float* dense_b = (const float*)d_in[11];
  const float* user_weights = (const float*)d_in[12];
  const float* user_bias = (const float*)d_in[13];
  const float* item_weights = (const float*)d_in[14];
  const float* item_bias = (const float*)d_in[15];
  const float* last_w = (const float*)d_in[16];
  const float* last_b = (const float*)d_in[17];

  char* ws = (char*)d_ws;
  __hip_bfloat16* news_cnn = (__hip_bfloat16*)ws;        // 12.8 MB
  ws += (size_t)NNEWS * DIM * 2;
  __hip_bfloat16* dwt = (__hip_bfloat16*)ws;             // 262,144 B
  ws += (size_t)DIM * FLAT2 * 2;
  __hip_bfloat16* iwt = (__hip_bfloat16*)ws;
  ws += (size_t)DIM * DIM * 2;
  __hip_bfloat16* uwt = (__hip_bfloat16*)ws;
  float* out = (float*)d_out;

  k_prep<<<(PREP_ELEMS + 255) / 256, 256, 0, stream>>>(
      dense_w, item_weights, user_weights, dwt, iwt, uwt);
  k_news<<<NEWS_BLOCKS, 256, 0, stream>>>(
      title, word_emb_matrix, conv_w, conv_b, dwt, dense_b, iwt, item_bias,
      news_cnn);
  k_back<<<BSZ, 512, 0, stream>>>(news_cnn, user_emb_matrix, uwt, user_bias,
                                  user_indices, news_indices, news_user,
                                  user_news, last_w, last_b, out);
}

// Round 15
// 185.853 us; speedup vs baseline: 1.7528x; 1.3226x over previous
//
#include <hip/hip_runtime.h>
#include <hip/hip_bf16.h>
#include <math.h>

#define BSZ 2048
#define NNEWS 50000
#define U_NB 30
#define N_NB 30
#define TITLE_LEN 10
#define W_EMB 50
#define DIM 128
#define ROUTIT 4
#define FLAT2 1024        // permuted, zero-padded K

#define CONV_BLOCKS (NNEWS / 8)                       // 6250
#define PREP_ELEMS (DIM * FLAT2 + 2 * DIM * DIM)      // 163,840
#define PREP_BLOCKS (PREP_ELEMS / 256)                // 640
#define DENSE_BLOCKS ((NNEWS + 63) / 64)              // 782

typedef __attribute__((ext_vector_type(8))) short bf16x8;
typedef __attribute__((ext_vector_type(4))) float f32x4;

__device__ __forceinline__ ushort bfbits(float v) {
  __hip_bfloat16 h = __float2bfloat16(v);
  ushort u;
  __builtin_memcpy(&u, &h, 2);
  return u;
}

// Build a bf16x8 A-frag = x[s..s+8) from a 16B-aligned 64-elem bf16 row.
__device__ __forceinline__ bf16x8 bfrag(const ushort* row, int s) {
  const char* p = reinterpret_cast<const char*>(row) + ((s * 2) & ~15);
  const uint4 lo = *reinterpret_cast<const uint4*>(p);
  const uint4 hi = *reinterpret_cast<const uint4*>(p + 16);
  const uint d0 = lo.x, d1 = lo.y, d2 = lo.z, d3 = lo.w;
  const uint d4 = hi.x, d5 = hi.y, d6 = hi.z, d7 = hi.w;
  const bool q2 = (s & 4) != 0;
  const uint e0 = q2 ? d2 : d0, e1 = q2 ? d3 : d1, e2 = q2 ? d4 : d2;
  const uint e3 = q2 ? d5 : d3, e4 = q2 ? d6 : d4, e5 = q2 ? d7 : d5;
  const bool q1 = (s & 2) != 0;
  const uint f0 = q1 ? e1 : e0, f1 = q1 ? e2 : e1, f2 = q1 ? e3 : e2;
  const uint f3 = q1 ? e4 : e3, f4 = q1 ? e5 : e4;
  const bool r1 = (s & 1) != 0;
  uint g[4];
  g[0] = r1 ? ((f0 >> 16) | (f1 << 16)) : f0;
  g[1] = r1 ? ((f1 >> 16) | (f2 << 16)) : f1;
  g[2] = r1 ? ((f2 >> 16) | (f3 << 16)) : f2;
  g[3] = r1 ? ((f3 >> 16) | (f4 << 16)) : f3;
  bf16x8 r;
  __builtin_memcpy(&r, g, 16);
  return r;
}

// ---------------------------------------------------------------------------
// k_front: blocks [0, CONV_BLOCKS) = MFMA Toeplitz conv (8 titles/block,
// ALL 10 row-frags hoisted per (title,jh) -> independent MFMA chains);
// blocks [CONV_BLOCKS, +PREP_BLOCKS) = weight prep.
// ---------------------------------------------------------------------------
__global__ __launch_bounds__(256, 4) void k_front(
    const int* __restrict__ title, const float* __restrict__ word_emb,
    const float* __restrict__ conv_w, const float* __restrict__ conv_b,
    const float* __restrict__ dw, const float* __restrict__ iw,
    const float* __restrict__ uw, __hip_bfloat16* __restrict__ flat,
    __hip_bfloat16* __restrict__ dwt, __hip_bfloat16* __restrict__ iwt,
    __hip_bfloat16* __restrict__ uwt) {
  const int tid = threadIdx.x;

  if (blockIdx.x >= CONV_BLOCKS) {  // ---- prep part ----
    const int idx = ((int)blockIdx.x - CONV_BLOCKS) * 256 + tid;
    if (idx < DIM * FLAT2) {
      const int col = idx & 127, k2 = idx >> 7;
      const int i = k2 & 3, X = k2 >> 2;
      const int c = X & 7, gkq = (X >> 3) & 3, jhq = (X >> 5) & 1, h = X >> 6;
      const int j = jhq * 16 + gkq * 4 + i;
      const float v = (j < 31) ? dw[(c * 124 + h * 31 + j) * 128 + col] : 0.f;
      dwt[col * FLAT2 + k2] = __float2bfloat16(v);
    } else if (idx < DIM * FLAT2 + DIM * DIM) {
      const int j = idx - DIM * FLAT2;
      const int o = j & 127, k = j >> 7;
      iwt[o * DIM + k] = __float2bfloat16(iw[j]);
    } else if (idx < PREP_ELEMS) {
      const int j = idx - DIM * FLAT2 - DIM * DIM;
      const int o = j & 127, k = j >> 7;
      uwt[o * DIM + k] = __float2bfloat16(uw[j]);
    }
    return;
  }

  // ---- conv part ----
  __shared__ int s_words[80];
  __shared__ __align__(16) ushort s_x[80 * 64];

  const int wv = tid >> 6, lane = tid & 63;
  const int base = blockIdx.x * 8;
  const int c = lane & 15, gk = lane >> 4;
  const int fr = lane & 15;

  bf16x8 b0, b1;
#pragma unroll
  for (int i = 0; i < 8; ++i) {
    const int k = gk * 8 + i;
    float v0 = 0.f, v1 = 0.f;
    if (c < 8 && k < 20) {
      v0 = conv_w[c * 40 + k];
      v1 = conv_w[c * 40 + 20 + k];
    }
    b0[i] = (short)bfbits(v0);
    b1[i] = (short)bfbits(v1);
  }
  const float cbias = (c < 8) ? conv_b[c] : 0.f;

  if (tid < 80) s_words[tid] = title[base * TITLE_LEN + tid];
  __syncthreads();

  {
    const float2* we2 = reinterpret_cast<const float2*>(word_emb);
#pragma unroll
    for (int i = 0; i < 3; ++i) {
      const int u = tid + i * 256;
      if (u < 640) {
        const int row = u >> 3, slot = u & 7;
        ushort o[8];
#pragma unroll
        for (int p = 0; p < 4; ++p) {
          const int c2 = slot * 4 + p;
          float2 v = make_float2(0.f, 0.f);
          if (c2 < 25) v = we2[(long long)s_words[row] * 25 + c2];
          o[2 * p] = bfbits(v.x);
          o[2 * p + 1] = bfbits(v.y);
        }
        *reinterpret_cast<uint4*>(&s_x[row * 64 + slot * 8]) =
            *reinterpret_cast<const uint4*>(o);
      }
    }
  }
  __syncthreads();

  // conv via MFMA; ALL 10 row frags hoisted per (title,jh) so the 8 MFMA
  // chains (2-deep) are independent and the loads share one latency window.
  ushort* fl = reinterpret_cast<ushort*>(flat);
#pragma unroll 1
  for (int tt = 0; tt < 2; ++tt) {
    const int t = wv * 2 + tt;
    const ushort* xb = &s_x[t * 640];
    ushort* gout = &fl[(size_t)(base + t) * FLAT2];
#pragma unroll 1
    for (int jh = 0; jh < 2; ++jh) {
      const int s = jh * 16 + fr + gk * 8;
      bf16x8 rf[10];
#pragma unroll
      for (int r = 0; r < 10; ++r) rf[r] = bfrag(xb + r * 64, s);
#pragma unroll
      for (int h = 0; h < 4; ++h) {
        f32x4 d0 = (f32x4){0.f, 0.f, 0.f, 0.f};
        f32x4 d1 = (f32x4){0.f, 0.f, 0.f, 0.f};
        d0 = __builtin_amdgcn_mfma_f32_16x16x32_bf16(rf[2 * h], b0, d0, 0, 0, 0);
        d0 = __builtin_amdgcn_mfma_f32_16x16x32_bf16(rf[2 * h + 1], b1, d0, 0, 0, 0);
        d1 = __builtin_amdgcn_mfma_f32_16x16x32_bf16(rf[2 * h + 1], b0, d1, 0, 0, 0);
        d1 = __builtin_amdgcn_mfma_f32_16x16x32_bf16(rf[2 * h + 2], b1, d1, 0, 0, 0);
        if (c < 8) {
          ushort w[4];
#pragma unroll
          for (int i2 = 0; i2 < 4; ++i2)
            w[i2] = bfbits(fmaxf(fmaxf(d0[i2], d1[i2]) + cbias, 0.f));
          *reinterpret_cast<uint2*>(&gout[(h * 64 + jh * 32 + gk * 8 + c) * 4]) =
              *reinterpret_cast<const uint2*>(w);
        }
      }
    }
  }
}

// ---------------------------------------------------------------------------
// k_dense: [64 x 1024]@[1024 x 128] (+b, relu) then @[128 x 128] (+b, relu).
// ---------------------------------------------------------------------------
__global__ __launch_bounds__(256, 2) void k_dense(
    const __hip_bfloat16* __restrict__ flat,
    const __hip_bfloat16* __restrict__ dwt, const float* __restrict__ dense_b,
    const __hip_bfloat16* __restrict__ iwt, const float* __restrict__ item_b,
    __hip_bfloat16* __restrict__ news_cnn) {
  __shared__ __align__(16) char lds[18432];
  ushort* A0 = (ushort*)lds;
  ushort* A1 = (ushort*)(lds + 9216);
  ushort* c1 = (ushort*)lds;

  const int tid = threadIdx.x;
  const int wv = tid >> 6, lane = tid & 63;
  const int fr = lane & 15, gk = lane >> 4;
  const int lrow0 = min((int)blockIdx.x * 64, NNEWS - 64);
  const ushort* fl = (const ushort*)flat;
  const ushort* dwp = (const ushort*)dwt;

  uint4 pA[2];
#define LD_A(KS)                                                              \
  {                                                                           \
    _Pragma("unroll") for (int q = 0; q < 2; ++q) {                           \
      const int uu = tid + q * 256;                                           \
      pA[q] = *reinterpret_cast<const uint4*>(                                \
          &fl[(size_t)(lrow0 + (uu >> 3)) * FLAT2 + (KS) * 64 + (uu & 7) * 8]); \
    }                                                                         \
  }
#define ST_A(BUF)                                                             \
  {                                                                           \
    _Pragma("unroll") for (int q = 0; q < 2; ++q) {                           \
      const int uu = tid + q * 256;                                           \
      *reinterpret_cast<uint4*>(&(BUF)[(uu >> 3) * 72 + (uu & 7) * 8]) = pA[q]; \
    }                                                                         \
  }
#define LD_B(DST, KS)                                                         \
  {                                                                           \
    _Pragma("unroll") for (int nn = 0; nn < 2; ++nn)                          \
        _Pragma("unroll") for (int qq = 0; qq < 2; ++qq) {                    \
      (DST)[nn * 2 + qq] = *reinterpret_cast<const bf16x8*>(                  \
          &dwp[(wv * 32 + nn * 16 + fr) * FLAT2 + (KS) * 64 + qq * 32 +       \
               gk * 8]);                                                      \
    }                                                                         \
  }

  LD_A(0);
  ST_A(A0);
  LD_A(1);
  bf16x8 bA[4];
  LD_B(bA, 0);
  __syncthreads();

  f32x4 acc[4][2];
#pragma unroll
  for (int m = 0; m < 4; ++m)
#pragma unroll
    for (int n2 = 0; n2 < 2; ++n2) acc[m][n2] = (f32x4){0.f, 0.f, 0.f, 0.f};

  for (int ks = 0; ks < 16; ++ks) {
    const ushort* cA = (ks & 1) ? A1 : A0;
    bf16x8 bN[4];
    if (ks < 15) {
      LD_B(bN, ks + 1);
    } else {
#pragma unroll
      for (int z = 0; z < 4; ++z) bN[z] = bA[z];
    }
    bf16x8 af[2][4];
#pragma unroll
    for (int kk = 0; kk < 2; ++kk)
#pragma unroll
      for (int m = 0; m < 4; ++m)
        af[kk][m] = *reinterpret_cast<const bf16x8*>(
            &cA[(m * 16 + fr) * 72 + kk * 32 + gk * 8]);
#pragma unroll
    for (int kk = 0; kk < 2; ++kk)
#pragma unroll
      for (int m = 0; m < 4; ++m)
#pragma unroll
        for (int n2 = 0; n2 < 2; ++n2)
          acc[m][n2] = __builtin_amdgcn_mfma_f32_16x16x32_bf16(
              af[kk][m], bA[n2 * 2 + kk], acc[m][n2], 0, 0, 0);
    if (ks < 15) {
      if (ks & 1) {
        ST_A(A0);
      } else {
        ST_A(A1);
      }
    }
    if (ks < 14) LD_A(ks + 2);
    __syncthreads();
#pragma unroll
    for (int z = 0; z < 4; ++z) bA[z] = bN[z];
  }
#undef LD_A
#undef ST_A
#undef LD_B

#pragma unroll
  for (int n2 = 0; n2 < 2; ++n2) {
    const int col = wv * 32 + n2 * 16 + fr;
    const float bb = dense_b[col];
#pragma unroll
    for (int m = 0; m < 4; ++m)
#pragma unroll
      for (int r = 0; r < 4; ++r)
        c1[(m * 16 + gk * 4 + r) * 136 + col] =
            bfbits(fmaxf(acc[m][n2][r] + bb, 0.f));
  }
  __syncthreads();

  const ushort* iwp = (const ushort*)iwt;
  f32x4 a2[4][2];
#pragma unroll
  for (int m = 0; m < 4; ++m)
#pragma unroll
    for (int n2 = 0; n2 < 2; ++n2) a2[m][n2] = (f32x4){0.f, 0.f, 0.f, 0.f};
#pragma unroll
  for (int kk = 0; kk < 4; ++kk) {
    bf16x8 af[4], bfr[2];
#pragma unroll
    for (int m = 0; m < 4; ++m)
      af[m] = *reinterpret_cast<const bf16x8*>(
          &c1[(m * 16 + fr) * 136 + kk * 32 + gk * 8]);
#pragma unroll
    for (int n2 = 0; n2 < 2; ++n2)
      bfr[n2] = *reinterpret_cast<const bf16x8*>(
          &iwp[(wv * 32 + n2 * 16 + fr) * DIM + kk * 32 + gk * 8]);
#pragma unroll
    for (int m = 0; m < 4; ++m)
#pragma unroll
      for (int n2 = 0; n2 < 2; ++n2)
        a2[m][n2] = __builtin_amdgcn_mfma_f32_16x16x32_bf16(
            af[m], bfr[n2], a2[m][n2], 0, 0, 0);
  }

#pragma unroll
  for (int n2 = 0; n2 < 2; ++n2) {
    const int col = wv * 32 + n2 * 16 + fr;
    const float bb = item_b[col];
#pragma unroll
    for (int m = 0; m < 4; ++m)
#pragma unroll
      for (int r = 0; r < 4; ++r) {
        const int row = m * 16 + gk * 4 + r;
        news_cnn[(size_t)(lrow0 + row) * DIM + col] =
            __float2bfloat16(fmaxf(a2[m][n2][r] + bb, 0.f));
      }
  }
}

// ---------------------------------------------------------------------------
// k_back: 512 thr/block, block b (unchanged from R12).
// ---------------------------------------------------------------------------
__device__ __forceinline__ float gsum16(float v) {
  v += __shfl_xor(v, 1, 16);
  v += __shfl_xor(v, 2, 16);
  v += __shfl_xor(v, 4, 16);
  v += __shfl_xor(v, 8, 16);
  return v;
}

__global__ __launch_bounds__(512) void k_back(
    const __hip_bfloat16* __restrict__ news_cnn,
    const float* __restrict__ user_emb, const __hip_bfloat16* __restrict__ uwt,
    const float* __restrict__ user_b, const int* __restrict__ user_indices,
    const int* __restrict__ news_indices, const int* __restrict__ news_user,
    const int* __restrict__ user_news, const float* __restrict__ last_w,
    const float* __restrict__ last_b, float* __restrict__ out) {
  __shared__ int s_uid[32];
  __shared__ int s_nid[32];
  __shared__ __align__(16) __hip_bfloat16 s_e[32][136];
  __shared__ __align__(16) float zf2[2][30][132];
  __shared__ __align__(16) float xn2[2][128];
  __shared__ __align__(16) float uu2[2][128];
  __shared__ __align__(16) float pp2[2][30][8];
  __shared__ float s_r[2];

  const int b = blockIdx.x, tid = threadIdx.x;

  if (tid < 32) {
    int uid;
    if (tid == 0 || tid == 31)
      uid = user_indices[b];
    else
      uid = news_user[(long long)news_indices[b] * U_NB + (tid - 1)];
    s_uid[tid] = uid;
  }
  if (tid >= 64 && tid < 94)
    s_nid[tid - 64] = user_news[(long long)user_indices[b] * N_NB + (tid - 64)];
  __syncthreads();

  const int hs = tid >> 8;
  const int t = tid & 255;
  float(*zf)[132] = zf2[hs];
  float* xn = xn2[hs];
  float* uu = uu2[hs];
  float(*pp)[8] = pp2[hs];

  if (tid < 256) {
#pragma unroll
    for (int i = 0; i < 4; ++i) {
      const int u = tid + i * 256;
      const int row = u >> 5, d4 = u & 31;
      const float4 v = *reinterpret_cast<const float4*>(
          &user_emb[(long long)s_uid[row] * DIM + d4 * 4]);
      __hip_bfloat16* p = &s_e[row][d4 * 4];
      p[0] = __float2bfloat16(v.x);
      p[1] = __float2bfloat16(v.y);
      p[2] = __float2bfloat16(v.z);
      p[3] = __float2bfloat16(v.w);
    }
  } else {
    if (t < 240) {
      const int k = t >> 3, q = t & 7;
      const ushort* src =
          reinterpret_cast<const ushort*>(news_cnn + (long long)s_nid[k] * DIM);
      ushort h16[16];
      *reinterpret_cast<uint4*>(&h16[0]) =
          *reinterpret_cast<const uint4*>(&src[q * 16]);
      *reinterpret_cast<uint4*>(&h16[8]) =
          *reinterpret_cast<const uint4*>(&src[q * 16 + 8]);
      float f[16];
#pragma unroll
      for (int i = 0; i < 16; ++i) {
        const uint bits = ((uint)h16[i]) << 16;
        __builtin_memcpy(&f[i], &bits, 4);
      }
#pragma unroll
      for (int v4 = 0; v4 < 4; ++v4)
        *reinterpret_cast<f32x4*>(&zf2[1][k][q * 16 + v4 * 4]) =
            *reinterpret_cast<f32x4*>(&f[v4 * 4]);
    } else {
      const int j = t - 240;
      const ushort* src = reinterpret_cast<const ushort*>(
          news_cnn + (long long)news_indices[b] * DIM);
      ushort h8[8];
      *reinterpret_cast<uint4*>(h8) =
          *reinterpret_cast<const uint4*>(&src[j * 8]);
#pragma unroll
      for (int i = 0; i < 8; ++i) {
        const uint bits = ((uint)h8[i]) << 16;
        float fv;
        __builtin_memcpy(&fv, &bits, 4);
        xn2[0][j * 8 + i] = fv;
      }
    }
  }
  __syncthreads();

  float z16[16];
  const int kk = t >> 3, cc = t & 7;
  if (tid < 256) {
    const int wv = tid >> 6, lane = tid & 63;
    const int fr = lane & 15, gk = lane >> 4;
    const ushort* uwp = (const ushort*)uwt;
    f32x4 acc[2][2];
#pragma unroll
    for (int m = 0; m < 2; ++m)
#pragma unroll
      for (int n = 0; n < 2; ++n) acc[m][n] = (f32x4){0.f, 0.f, 0.f, 0.f};
#pragma unroll
    for (int ks = 0; ks < 4; ++ks) {
      bf16x8 af[2], bfr[2];
#pragma unroll
      for (int m = 0; m < 2; ++m)
        af[m] = *reinterpret_cast<const bf16x8*>(
            &s_e[m * 16 + fr][ks * 32 + gk * 8]);
#pragma unroll
      for (int n = 0; n < 2; ++n)
        bfr[n] = *reinterpret_cast<const bf16x8*>(
            &uwp[(wv * 32 + n * 16 + fr) * DIM + ks * 32 + gk * 8]);
#pragma unroll
      for (int m = 0; m < 2; ++m)
#pragma unroll
        for (int n = 0; n < 2; ++n)
          acc[m][n] = __builtin_amdgcn_mfma_f32_16x16x32_bf16(
              af[m], bfr[n], acc[m][n], 0, 0, 0);
    }
#pragma unroll
    for (int n = 0; n < 2; ++n) {
      const int col = wv * 32 + n * 16 + fr;
      const float bb = user_b[col];
#pragma unroll
      for (int m = 0; m < 2; ++m)
#pragma unroll
        for (int r = 0; r < 4; ++r) {
          const int row = m * 16 + gk * 4 + r;
          const float val = fmaxf(acc[m][n][r] + bb, 0.f);
          if (row == 0)
            xn2[1][col] = val;
          else if (row < 31)
            zf2[0][row - 1][col] = val;
        }
    }
  } else if (t < 240) {
    float ss = 0.f;
#pragma unroll
    for (int d = 0; d < 16; ++d) {
      z16[d] = zf2[1][kk][cc * 16 + d];
      ss += z16[d] * z16[d];
    }
    const float inv = 1.f / (sqrtf(ss) + 1e-9f);
#pragma unroll
    for (int d = 0; d < 16; ++d) {
      z16[d] *= inv;
      zf2[1][kk][cc * 16 + d] = z16[d];
    }
  }
  __syncthreads();

  if (hs == 0 && t < 240) {
    float ss = 0.f;
#pragma unroll
    for (int d = 0; d < 16; ++d) {
      z16[d] = zf2[0][kk][cc * 16 + d];
      ss += z16[d] * z16[d];
    }
    const float inv = 1.f / (sqrtf(ss) + 1e-9f);
#pragma unroll
    for (int d = 0; d < 16; ++d) {
      z16[d] *= inv;
      zf2[0][kk][cc * 16 + d] = z16[d];
    }
  }
  if (t < 128) {
    float xv = xn[t];
    xv = xv / (sqrtf(gsum16(xv * xv)) + 1e-9f);
    xn[t] = xv;
    uu[t] = xv;
  }
  __syncthreads();

  for (int it = 0; it < ROUTIT; ++it) {
    if (t < 240) {
      float dot = 0.f;
#pragma unroll
      for (int d = 0; d < 16; ++d) dot += z16[d] * uu[cc * 16 + d];
      float m8 = dot;
      m8 = fmaxf(m8, __shfl_xor(m8, 1, 8));
      m8 = fmaxf(m8, __shfl_xor(m8, 2, 8));
      m8 = fmaxf(m8, __shfl_xor(m8, 4, 8));
      float e = expf(dot - m8);
      float s8 = e;
      s8 += __shfl_xor(s8, 1, 8);
      s8 += __shfl_xor(s8, 2, 8);
      s8 += __shfl_xor(s8, 4, 8);
      pp[kk][cc] = e / s8;
    }
    __syncthreads();
    if (t < 128) {
      const int c2 = t >> 4;
      float agg = xn[t];
#pragma unroll
      for (int k = 0; k < 30; ++k) agg += pp[k][c2] * zf[k][t];
      uu[t] = agg / (sqrtf(gsum16(agg * agg)) + 1e-9f);
    }
    __syncthreads();
  }

  if (tid < 128) {
    float xm = last_b[tid], ym = xm;
    for (int k = 0; k < DIM; k += 4) {
#pragma unroll
      for (int i = 0; i < 4; ++i) {
        const float w = last_w[(k + i) * DIM + tid];
        xm += uu2[1][k + i] * w;
        ym += uu2[0][k + i] * w;
      }
    }
    float prod = xm * ym;
#pragma unroll
    for (int off = 1; off < 64; off <<= 1) prod += __shfl_xor(prod, off, 64);
    if ((tid & 63) == 0) s_r[tid >> 6] = prod;
  }
  __syncthreads();
  if (tid == 0) out[b] = 1.f / (1.f + expf(-(s_r[0] + s_r[1])));
}

// ---------------------------------------------------------------------------
extern "C" void kernel_launch(void* const* d_in, const int* in_sizes, int n_in,
                              void* d_out, int out_size, void* d_ws,
                              size_t ws_size, hipStream_t stream) {
  (void)in_sizes; (void)n_in; (void)out_size; (void)ws_size;
  const int* user_indices = (const int*)d_in[0];
  const int* news_indices = (const int*)d_in[1];
  const int* news_user = (const int*)d_in[3];
  const int* user_news = (const int*)d_in[4];
  const int* title = (const int*)d_in[5];
  const float* user_emb_matrix = (const float*)d_in[6];
  const float* word_emb_matrix = (const float*)d_in[7];
  const float* conv_w = (const float*)d_in[8];
  const float* conv_b = (const float*)d_in[9];
  const float* dense_w = (const float*)d_in[10];
  const float* dense_b = (const float*)d_in[11];
  const float* user_weights = (const float*)d_in[12];
  const float* user_bias = (const float*)d_in[13];
  const float* item_weights = (const float*)d_in[14];
  const float* item_bias = (const float*)d_in[15];
  const float* last_w = (const float*)d_in[16];
  const float* last_b = (const float*)d_in[17];

  char* ws = (char*)d_ws;
  __hip_bfloat16* flat = (__hip_bfloat16*)ws;            // 102.4 MB
  ws += (size_t)NNEWS * FLAT2 * 2;
  __hip_bfloat16* news_cnn = (__hip_bfloat16*)ws;        // 12.8 MB
  ws += (size_t)NNEWS * DIM * 2;
  __hip_bfloat16* dwt = (__hip_bfloat16*)ws;             // 262,144 B
  ws += (size_t)DIM * FLAT2 * 2;
  __hip_bfloat16* iwt = (__hip_bfloat16*)ws;
  ws += (size_t)DIM * DIM * 2;
  __hip_bfloat16* uwt = (__hip_bfloat16*)ws;
  float* out = (float*)d_out;

  k_front<<<CONV_BLOCKS + PREP_BLOCKS, 256, 0, stream>>>(
      title, word_emb_matrix, conv_w, conv_b, dense_w, item_weights,
      user_weights, flat, dwt, iwt, uwt);
  k_dense<<<DENSE_BLOCKS, 256, 0, stream>>>(flat, dwt, dense_b, iwt, item_bias,
                                            news_cnn);
  k_back<<<BSZ, 512, 0, stream>>>(news_cnn, user_emb_matrix, uwt, user_bias,
                                  user_indices, news_indices, news_user,
                                  user_news, last_w, last_b, out);
}

// Round 16
// 176.590 us; speedup vs baseline: 1.8448x; 1.0525x over previous
//
#include <hip/hip_runtime.h>
#include <hip/hip_bf16.h>
#include <math.h>

#define BSZ 2048
#define NNEWS 50000
#define U_NB 30
#define N_NB 30
#define TITLE_LEN 10
#define W_EMB 50
#define DIM 128
#define ROUTIT 4
#define FLAT2 1024        // permuted, zero-padded K

#define CONV_BLOCKS (NNEWS / 8)                       // 6250
#define PREP_ELEMS (DIM * FLAT2 + 2 * DIM * DIM)      // 163,840
#define PREP_BLOCKS (PREP_ELEMS / 256)                // 640
#define DENSE_BLOCKS ((NNEWS + 63) / 64)              // 782

typedef __attribute__((ext_vector_type(8))) short bf16x8;
typedef __attribute__((ext_vector_type(4))) float f32x4;

__device__ __forceinline__ ushort bfbits(float v) {
  __hip_bfloat16 h = __float2bfloat16(v);
  ushort u;
  __builtin_memcpy(&u, &h, 2);
  return u;
}

// Build a bf16x8 A-frag = x[s..s+8) from a 16B-aligned 64-elem bf16 row.
__device__ __forceinline__ bf16x8 bfrag(const ushort* row, int s) {
  const char* p = reinterpret_cast<const char*>(row) + ((s * 2) & ~15);
  const uint4 lo = *reinterpret_cast<const uint4*>(p);
  const uint4 hi = *reinterpret_cast<const uint4*>(p + 16);
  const uint d0 = lo.x, d1 = lo.y, d2 = lo.z, d3 = lo.w;
  const uint d4 = hi.x, d5 = hi.y, d6 = hi.z, d7 = hi.w;
  const bool q2 = (s & 4) != 0;
  const uint e0 = q2 ? d2 : d0, e1 = q2 ? d3 : d1, e2 = q2 ? d4 : d2;
  const uint e3 = q2 ? d5 : d3, e4 = q2 ? d6 : d4, e5 = q2 ? d7 : d5;
  const bool q1 = (s & 2) != 0;
  const uint f0 = q1 ? e1 : e0, f1 = q1 ? e2 : e1, f2 = q1 ? e3 : e2;
  const uint f3 = q1 ? e4 : e3, f4 = q1 ? e5 : e4;
  const bool r1 = (s & 1) != 0;
  uint g[4];
  g[0] = r1 ? ((f0 >> 16) | (f1 << 16)) : f0;
  g[1] = r1 ? ((f1 >> 16) | (f2 << 16)) : f1;
  g[2] = r1 ? ((f2 >> 16) | (f3 << 16)) : f2;
  g[3] = r1 ? ((f3 >> 16) | (f4 << 16)) : f3;
  bf16x8 r;
  __builtin_memcpy(&r, g, 16);
  return r;
}

// ---------------------------------------------------------------------------
// k_front: blocks [0, CONV_BLOCKS): BARRIER-FREE wave-autonomous MFMA conv —
// each wave owns 2 titles end-to-end (shfl word-broadcast, private s_x
// region, one lgkmcnt fence, no __syncthreads). LB(256,8) for ~32 waves/CU.
// Blocks [CONV_BLOCKS, +PREP_BLOCKS) = weight prep.
// ---------------------------------------------------------------------------
__global__ __launch_bounds__(256, 8) void k_front(
    const int* __restrict__ title, const float* __restrict__ word_emb,
    const float* __restrict__ conv_w, const float* __restrict__ conv_b,
    const float* __restrict__ dw, const float* __restrict__ iw,
    const float* __restrict__ uw, __hip_bfloat16* __restrict__ flat,
    __hip_bfloat16* __restrict__ dwt, __hip_bfloat16* __restrict__ iwt,
    __hip_bfloat16* __restrict__ uwt) {
  const int tid = threadIdx.x;

  if (blockIdx.x >= CONV_BLOCKS) {  // ---- prep part ----
    const int idx = ((int)blockIdx.x - CONV_BLOCKS) * 256 + tid;
    if (idx < DIM * FLAT2) {
      const int col = idx & 127, k2 = idx >> 7;
      const int i = k2 & 3, X = k2 >> 2;
      const int c = X & 7, gkq = (X >> 3) & 3, jhq = (X >> 5) & 1, h = X >> 6;
      const int j = jhq * 16 + gkq * 4 + i;
      const float v = (j < 31) ? dw[(c * 124 + h * 31 + j) * 128 + col] : 0.f;
      dwt[col * FLAT2 + k2] = __float2bfloat16(v);
    } else if (idx < DIM * FLAT2 + DIM * DIM) {
      const int j = idx - DIM * FLAT2;
      const int o = j & 127, k = j >> 7;
      iwt[o * DIM + k] = __float2bfloat16(iw[j]);
    } else if (idx < PREP_ELEMS) {
      const int j = idx - DIM * FLAT2 - DIM * DIM;
      const int o = j & 127, k = j >> 7;
      uwt[o * DIM + k] = __float2bfloat16(uw[j]);
    }
    return;
  }

  // ---- conv part (wave-local, no block barriers) ----
  __shared__ __align__(16) ushort s_x[4][20 * 64];  // 10,240 B

  const int wv = tid >> 6, lane = tid & 63;
  const int base = blockIdx.x * 8 + wv * 2;  // this wave's 2 titles
  const int c = lane & 15, gk = lane >> 4;
  const int fr = lane & 15;

  // conv B-frags (weights); taps >=20 zeroed in B
  bf16x8 b0, b1;
#pragma unroll
  for (int i = 0; i < 8; ++i) {
    const int k = gk * 8 + i;
    float v0 = 0.f, v1 = 0.f;
    if (c < 8 && k < 20) {
      v0 = conv_w[c * 40 + k];
      v1 = conv_w[c * 40 + 20 + k];
    }
    b0[i] = (short)bfbits(v0);
    b1[i] = (short)bfbits(v1);
  }
  const float cbias = (c < 8) ? conv_b[c] : 0.f;

  // word ids: lanes 0..19 hold this wave's 20 words (2 titles x 10)
  const int wid = (lane < 20) ? title[base * TITLE_LEN + lane] : 0;

  // gather 20 rows x 25 float2 -> bf16 pairs (u32 LDS writes), wave-local
  {
    const float2* we2 = reinterpret_cast<const float2*>(word_emb);
    ushort* xw = &s_x[wv][0];
#pragma unroll
    for (int i = 0; i < 8; ++i) {
      const int u = lane + i * 64;
      if (u < 500) {
        const int row = u / 25, col = u - row * 25;
        const int word = __shfl(wid, row);
        const float2 v = we2[(long long)word * 25 + col];
        const uint pk = (uint)bfbits(v.x) | ((uint)bfbits(v.y) << 16);
        *reinterpret_cast<uint*>(&xw[row * 64 + col * 2]) = pk;
      }
    }
    // zero-fill elems 50..63 of each row (7 u32 slots x 20 rows = 140)
#pragma unroll
    for (int i = 0; i < 3; ++i) {
      const int u = lane + i * 64;
      if (u < 140) {
        const int row = u / 7, slot = u - row * 7;
        *reinterpret_cast<uint*>(&xw[row * 64 + 50 + slot * 2]) = 0u;
      }
    }
  }
  // fence: this wave's LDS writes complete before its reads below
  asm volatile("s_waitcnt lgkmcnt(0)" ::: "memory");

  // conv via MFMA, rolling 3-frag window; direct-global epilogue
  ushort* fl = reinterpret_cast<ushort*>(flat);
#pragma unroll 1
  for (int tt = 0; tt < 2; ++tt) {
    const ushort* xb = &s_x[wv][tt * 640];  // 10 rows x 64
    ushort* gout = &fl[(size_t)(base + tt) * FLAT2];
#pragma unroll 1
    for (int jh = 0; jh < 2; ++jh) {
      const int s = jh * 16 + fr + gk * 8;
      bf16x8 fprev = bfrag(xb, s);
#pragma unroll
      for (int h = 0; h < 4; ++h) {
        const bf16x8 fmid = bfrag(xb + (2 * h + 1) * 64, s);
        const bf16x8 fnext = bfrag(xb + (2 * h + 2) * 64, s);
        f32x4 d0 = (f32x4){0.f, 0.f, 0.f, 0.f};
        f32x4 d1 = (f32x4){0.f, 0.f, 0.f, 0.f};
        d0 = __builtin_amdgcn_mfma_f32_16x16x32_bf16(fprev, b0, d0, 0, 0, 0);
        d0 = __builtin_amdgcn_mfma_f32_16x16x32_bf16(fmid, b1, d0, 0, 0, 0);
        d1 = __builtin_amdgcn_mfma_f32_16x16x32_bf16(fmid, b0, d1, 0, 0, 0);
        d1 = __builtin_amdgcn_mfma_f32_16x16x32_bf16(fnext, b1, d1, 0, 0, 0);
        if (c < 8) {
          ushort w[4];
#pragma unroll
          for (int i2 = 0; i2 < 4; ++i2)
            w[i2] = bfbits(fmaxf(fmaxf(d0[i2], d1[i2]) + cbias, 0.f));
          *reinterpret_cast<uint2*>(&gout[(h * 64 + jh * 32 + gk * 8 + c) * 4]) =
              *reinterpret_cast<const uint2*>(w);
        }
        fprev = fnext;
      }
    }
  }
}

// ---------------------------------------------------------------------------
// k_dense: [64 x 1024]@[1024 x 128] (+b, relu) then @[128 x 128] (+b, relu).
// ---------------------------------------------------------------------------
__global__ __launch_bounds__(256, 2) void k_dense(
    const __hip_bfloat16* __restrict__ flat,
    const __hip_bfloat16* __restrict__ dwt, const float* __restrict__ dense_b,
    const __hip_bfloat16* __restrict__ iwt, const float* __restrict__ item_b,
    __hip_bfloat16* __restrict__ news_cnn) {
  __shared__ __align__(16) char lds[18432];
  ushort* A0 = (ushort*)lds;
  ushort* A1 = (ushort*)(lds + 9216);
  ushort* c1 = (ushort*)lds;

  const int tid = threadIdx.x;
  const int wv = tid >> 6, lane = tid & 63;
  const int fr = lane & 15, gk = lane >> 4;
  const int lrow0 = min((int)blockIdx.x * 64, NNEWS - 64);
  const ushort* fl = (const ushort*)flat;
  const ushort* dwp = (const ushort*)dwt;

  uint4 pA[2];
#define LD_A(KS)                                                              \
  {                                                                           \
    _Pragma("unroll") for (int q = 0; q < 2; ++q) {                           \
      const int uu = tid + q * 256;                                           \
      pA[q] = *reinterpret_cast<const uint4*>(                                \
          &fl[(size_t)(lrow0 + (uu >> 3)) * FLAT2 + (KS) * 64 + (uu & 7) * 8]); \
    }                                                                         \
  }
#define ST_A(BUF)                                                             \
  {                                                                           \
    _Pragma("unroll") for (int q = 0; q < 2; ++q) {                           \
      const int uu = tid + q * 256;                                           \
      *reinterpret_cast<uint4*>(&(BUF)[(uu >> 3) * 72 + (uu & 7) * 8]) = pA[q]; \
    }                                                                         \
  }
#define LD_B(DST, KS)                                                         \
  {                                                                           \
    _Pragma("unroll") for (int nn = 0; nn < 2; ++nn)                          \
        _Pragma("unroll") for (int qq = 0; qq < 2; ++qq) {                    \
      (DST)[nn * 2 + qq] = *reinterpret_cast<const bf16x8*>(                  \
          &dwp[(wv * 32 + nn * 16 + fr) * FLAT2 + (KS) * 64 + qq * 32 +       \
               gk * 8]);                                                      \
    }                                                                         \
  }

  LD_A(0);
  ST_A(A0);
  LD_A(1);
  bf16x8 bA[4];
  LD_B(bA, 0);
  __syncthreads();

  f32x4 acc[4][2];
#pragma unroll
  for (int m = 0; m < 4; ++m)
#pragma unroll
    for (int n2 = 0; n2 < 2; ++n2) acc[m][n2] = (f32x4){0.f, 0.f, 0.f, 0.f};

  for (int ks = 0; ks < 16; ++ks) {
    const ushort* cA = (ks & 1) ? A1 : A0;
    bf16x8 bN[4];
    if (ks < 15) {
      LD_B(bN, ks + 1);
    } else {
#pragma unroll
      for (int z = 0; z < 4; ++z) bN[z] = bA[z];
    }
    bf16x8 af[2][4];
#pragma unroll
    for (int kk = 0; kk < 2; ++kk)
#pragma unroll
      for (int m = 0; m < 4; ++m)
        af[kk][m] = *reinterpret_cast<const bf16x8*>(
            &cA[(m * 16 + fr) * 72 + kk * 32 + gk * 8]);
#pragma unroll
    for (int kk = 0; kk < 2; ++kk)
#pragma unroll
      for (int m = 0; m < 4; ++m)
#pragma unroll
        for (int n2 = 0; n2 < 2; ++n2)
          acc[m][n2] = __builtin_amdgcn_mfma_f32_16x16x32_bf16(
              af[kk][m], bA[n2 * 2 + kk], acc[m][n2], 0, 0, 0);
    if (ks < 15) {
      if (ks & 1) {
        ST_A(A0);
      } else {
        ST_A(A1);
      }
    }
    if (ks < 14) LD_A(ks + 2);
    __syncthreads();
#pragma unroll
    for (int z = 0; z < 4; ++z) bA[z] = bN[z];
  }
#undef LD_A
#undef ST_A
#undef LD_B

#pragma unroll
  for (int n2 = 0; n2 < 2; ++n2) {
    const int col = wv * 32 + n2 * 16 + fr;
    const float bb = dense_b[col];
#pragma unroll
    for (int m = 0; m < 4; ++m)
#pragma unroll
      for (int r = 0; r < 4; ++r)
        c1[(m * 16 + gk * 4 + r) * 136 + col] =
            bfbits(fmaxf(acc[m][n2][r] + bb, 0.f));
  }
  __syncthreads();

  const ushort* iwp = (const ushort*)iwt;
  f32x4 a2[4][2];
#pragma unroll
  for (int m = 0; m < 4; ++m)
#pragma unroll
    for (int n2 = 0; n2 < 2; ++n2) a2[m][n2] = (f32x4){0.f, 0.f, 0.f, 0.f};
#pragma unroll
  for (int kk = 0; kk < 4; ++kk) {
    bf16x8 af[4], bfr[2];
#pragma unroll
    for (int m = 0; m < 4; ++m)
      af[m] = *reinterpret_cast<const bf16x8*>(
          &c1[(m * 16 + fr) * 136 + kk * 32 + gk * 8]);
#pragma unroll
    for (int n2 = 0; n2 < 2; ++n2)
      bfr[n2] = *reinterpret_cast<const bf16x8*>(
          &iwp[(wv * 32 + n2 * 16 + fr) * DIM + kk * 32 + gk * 8]);
#pragma unroll
    for (int m = 0; m < 4; ++m)
#pragma unroll
      for (int n2 = 0; n2 < 2; ++n2)
        a2[m][n2] = __builtin_amdgcn_mfma_f32_16x16x32_bf16(
            af[m], bfr[n2], a2[m][n2], 0, 0, 0);
  }

#pragma unroll
  for (int n2 = 0; n2 < 2; ++n2) {
    const int col = wv * 32 + n2 * 16 + fr;
    const float bb = item_b[col];
#pragma unroll
    for (int m = 0; m < 4; ++m)
#pragma unroll
      for (int r = 0; r < 4; ++r) {
        const int row = m * 16 + gk * 4 + r;
        news_cnn[(size_t)(lrow0 + row) * DIM + col] =
            __float2bfloat16(fmaxf(a2[m][n2][r] + bb, 0.f));
      }
  }
}

// ---------------------------------------------------------------------------
// k_back: 512 thr/block, block b (unchanged from R12).
// ---------------------------------------------------------------------------
__device__ __forceinline__ float gsum16(float v) {
  v += __shfl_xor(v, 1, 16);
  v += __shfl_xor(v, 2, 16);
  v += __shfl_xor(v, 4, 16);
  v += __shfl_xor(v, 8, 16);
  return v;
}

__global__ __launch_bounds__(512) void k_back(
    const __hip_bfloat16* __restrict__ news_cnn,
    const float* __restrict__ user_emb, const __hip_bfloat16* __restrict__ uwt,
    const float* __restrict__ user_b, const int* __restrict__ user_indices,
    const int* __restrict__ news_indices, const int* __restrict__ news_user,
    const int* __restrict__ user_news, const float* __restrict__ last_w,
    const float* __restrict__ last_b, float* __restrict__ out) {
  __shared__ int s_uid[32];
  __shared__ int s_nid[32];
  __shared__ __align__(16) __hip_bfloat16 s_e[32][136];
  __shared__ __align__(16) float zf2[2][30][132];
  __shared__ __align__(16) float xn2[2][128];
  __shared__ __align__(16) float uu2[2][128];
  __shared__ __align__(16) float pp2[2][30][8];
  __shared__ float s_r[2];

  const int b = blockIdx.x, tid = threadIdx.x;

  if (tid < 32) {
    int uid;
    if (tid == 0 || tid == 31)
      uid = user_indices[b];
    else
      uid = news_user[(long long)news_indices[b] * U_NB + (tid - 1)];
    s_uid[tid] = uid;
  }
  if (tid >= 64 && tid < 94)
    s_nid[tid - 64] = user_news[(long long)user_indices[b] * N_NB + (tid - 64)];
  __syncthreads();

  const int hs = tid >> 8;
  const int t = tid & 255;
  float(*zf)[132] = zf2[hs];
  float* xn = xn2[hs];
  float* uu = uu2[hs];
  float(*pp)[8] = pp2[hs];

  if (tid < 256) {
#pragma unroll
    for (int i = 0; i < 4; ++i) {
      const int u = tid + i * 256;
      const int row = u >> 5, d4 = u & 31;
      const float4 v = *reinterpret_cast<const float4*>(
          &user_emb[(long long)s_uid[row] * DIM + d4 * 4]);
      __hip_bfloat16* p = &s_e[row][d4 * 4];
      p[0] = __float2bfloat16(v.x);
      p[1] = __float2bfloat16(v.y);
      p[2] = __float2bfloat16(v.z);
      p[3] = __float2bfloat16(v.w);
    }
  } else {
    if (t < 240) {
      const int k = t >> 3, q = t & 7;
      const ushort* src =
          reinterpret_cast<const ushort*>(news_cnn + (long long)s_nid[k] * DIM);
      ushort h16[16];
      *reinterpret_cast<uint4*>(&h16[0]) =
          *reinterpret_cast<const uint4*>(&src[q * 16]);
      *reinterpret_cast<uint4*>(&h16[8]) =
          *reinterpret_cast<const uint4*>(&src[q * 16 + 8]);
      float f[16];
#pragma unroll
      for (int i = 0; i < 16; ++i) {
        const uint bits = ((uint)h16[i]) << 16;
        __builtin_memcpy(&f[i], &bits, 4);
      }
#pragma unroll
      for (int v4 = 0; v4 < 4; ++v4)
        *reinterpret_cast<f32x4*>(&zf2[1][k][q * 16 + v4 * 4]) =
            *reinterpret_cast<f32x4*>(&f[v4 * 4]);
    } else {
      const int j = t - 240;
      const ushort* src = reinterpret_cast<const ushort*>(
          news_cnn + (long long)news_indices[b] * DIM);
      ushort h8[8];
      *reinterpret_cast<uint4*>(h8) =
          *reinterpret_cast<const uint4*>(&src[j * 8]);
#pragma unroll
      for (int i = 0; i < 8; ++i) {
        const uint bits = ((uint)h8[i]) << 16;
        float fv;
        __builtin_memcpy(&fv, &bits, 4);
        xn2[0][j * 8 + i] = fv;
      }
    }
  }
  __syncthreads();

  float z16[16];
  const int kk = t >> 3, cc = t & 7;
  if (tid < 256) {
    const int wv = tid >> 6, lane = tid & 63;
    const int fr = lane & 15, gk = lane >> 4;
    const ushort* uwp = (const ushort*)uwt;
    f32x4 acc[2][2];
#pragma unroll
    for (int m = 0; m < 2; ++m)
#pragma unroll
      for (int n = 0; n < 2; ++n) acc[m][n] = (f32x4){0.f, 0.f, 0.f, 0.f};
#pragma unroll
    for (int ks = 0; ks < 4; ++ks) {
      bf16x8 af[2], bfr[2];
#pragma unroll
      for (int m = 0; m < 2; ++m)
        af[m] = *reinterpret_cast<const bf16x8*>(
            &s_e[m * 16 + fr][ks * 32 + gk * 8]);
#pragma unroll
      for (int n = 0; n < 2; ++n)
        bfr[n] = *reinterpret_cast<const bf16x8*>(
            &uwp[(wv * 32 + n * 16 + fr) * DIM + ks * 32 + gk * 8]);
#pragma unroll
      for (int m = 0; m < 2; ++m)
#pragma unroll
        for (int n = 0; n < 2; ++n)
          acc[m][n] = __builtin_amdgcn_mfma_f32_16x16x32_bf16(
              af[m], bfr[n], acc[m][n], 0, 0, 0);
    }
#pragma unroll
    for (int n = 0; n < 2; ++n) {
      const int col = wv * 32 + n * 16 + fr;
      const float bb = user_b[col];
#pragma unroll
      for (int m = 0; m < 2; ++m)
#pragma unroll
        for (int r = 0; r < 4; ++r) {
          const int row = m * 16 + gk * 4 + r;
          const float val = fmaxf(acc[m][n][r] + bb, 0.f);
          if (row == 0)
            xn2[1][col] = val;
          else if (row < 31)
            zf2[0][row - 1][col] = val;
        }
    }
  } else if (t < 240) {
    float ss = 0.f;
#pragma unroll
    for (int d = 0; d < 16; ++d) {
      z16[d] = zf2[1][kk][cc * 16 + d];
      ss += z16[d] * z16[d];
    }
    const float inv = 1.f / (sqrtf(ss) + 1e-9f);
#pragma unroll
    for (int d = 0; d < 16; ++d) {
      z16[d] *= inv;
      zf2[1][kk][cc * 16 + d] = z16[d];
    }
  }
  __syncthreads();

  if (hs == 0 && t < 240) {
    float ss = 0.f;
#pragma unroll
    for (int d = 0; d < 16; ++d) {
      z16[d] = zf2[0][kk][cc * 16 + d];
      ss += z16[d] * z16[d];
    }
    const float inv = 1.f / (sqrtf(ss) + 1e-9f);
#pragma unroll
    for (int d = 0; d < 16; ++d) {
      z16[d] *= inv;
      zf2[0][kk][cc * 16 + d] = z16[d];
    }
  }
  if (t < 128) {
    float xv = xn[t];
    xv = xv / (sqrtf(gsum16(xv * xv)) + 1e-9f);
    xn[t] = xv;
    uu[t] = xv;
  }
  __syncthreads();

  for (int it = 0; it < ROUTIT; ++it) {
    if (t < 240) {
      float dot = 0.f;
#pragma unroll
      for (int d = 0; d < 16; ++d) dot += z16[d] * uu[cc * 16 + d];
      float m8 = dot;
      m8 = fmaxf(m8, __shfl_xor(m8, 1, 8));
      m8 = fmaxf(m8, __shfl_xor(m8, 2, 8));
      m8 = fmaxf(m8, __shfl_xor(m8, 4, 8));
      float e = expf(dot - m8);
      float s8 = e;
      s8 += __shfl_xor(s8, 1, 8);
      s8 += __shfl_xor(s8, 2, 8);
      s8 += __shfl_xor(s8, 4, 8);
      pp[kk][cc] = e / s8;
    }
    __syncthreads();
    if (t < 128) {
      const int c2 = t >> 4;
      float agg = xn[t];
#pragma unroll
      for (int k = 0; k < 30; ++k) agg += pp[k][c2] * zf[k][t];
      uu[t] = agg / (sqrtf(gsum16(agg * agg)) + 1e-9f);
    }
    __syncthreads();
  }

  if (tid < 128) {
    float xm = last_b[tid], ym = xm;
    for (int k = 0; k < DIM; k += 4) {
#pragma unroll
      for (int i = 0; i < 4; ++i) {
        const float w = last_w[(k + i) * DIM + tid];
        xm += uu2[1][k + i] * w;
        ym += uu2[0][k + i] * w;
      }
    }
    float prod = xm * ym;
#pragma unroll
    for (int off = 1; off < 64; off <<= 1) prod += __shfl_xor(prod, off, 64);
    if ((tid & 63) == 0) s_r[tid >> 6] = prod;
  }
  __syncthreads();
  if (tid == 0) out[b] = 1.f / (1.f + expf(-(s_r[0] + s_r[1])));
}

// ---------------------------------------------------------------------------
extern "C" void kernel_launch(void* const* d_in, const int* in_sizes, int n_in,
                              void* d_out, int out_size, void* d_ws,
                              size_t ws_size, hipStream_t stream) {
  (void)in_sizes; (void)n_in; (void)out_size; (void)ws_size;
  const int* user_indices = (const int*)d_in[0];
  const int* news_indices = (const int*)d_in[1];
  const int* news_user = (const int*)d_in[3];
  const int* user_news = (const int*)d_in[4];
  const int* title = (const int*)d_in[5];
  const float* user_emb_matrix = (const float*)d_in[6];
  const float* word_emb_matrix = (const float*)d_in[7];
  const float* conv_w = (const float*)d_in[8];
  const float* conv_b = (const float*)d_in[9];
  const float* dense_w = (const float*)d_in[10];
  const float* dense_b = (const float*)d_in[11];
  const float* user_weights = (const float*)d_in[12];
  const float* user_bias = (const float*)d_in[13];
  const float* item_weights = (const float*)d_in[14];
  const float* item_bias = (const float*)d_in[15];
  const float* last_w = (const float*)d_in[16];
  const float* last_b = (const float*)d_in[17];

  char* ws = (char*)d_ws;
  __hip_bfloat16* flat = (__hip_bfloat16*)ws;            // 102.4 MB
  ws += (size_t)NNEWS * FLAT2 * 2;
  __hip_bfloat16* news_cnn = (__hip_bfloat16*)ws;        // 12.8 MB
  ws += (size_t)NNEWS * DIM * 2;
  __hip_bfloat16* dwt = (__hip_bfloat16*)ws;             // 262,144 B
  ws += (size_t)DIM * FLAT2 * 2;
  __hip_bfloat16* iwt = (__hip_bfloat16*)ws;
  ws += (size_t)DIM * DIM * 2;
  __hip_bfloat16* uwt = (__hip_bfloat16*)ws;
  float* out = (float*)d_out;

  k_front<<<CONV_BLOCKS + PREP_BLOCKS, 256, 0, stream>>>(
      title, word_emb_matrix, conv_w, conv_b, dense_w, item_weights,
      user_weights, flat, dwt, iwt, uwt);
  k_dense<<<DENSE_BLOCKS, 256, 0, stream>>>(flat, dwt, dense_b, iwt, item_bias,
                                            news_cnn);
  k_back<<<BSZ, 512, 0, stream>>>(news_cnn, user_emb_matrix, uwt, user_bias,
                                  user_indices, news_indices, news_user,
                                  user_news, last_w, last_b, out);
}